// Round 4
// baseline (859.165 us; speedup 1.0000x reference)
//
#include <hip/hip_runtime.h>
#include <math.h>

#define NBAT 8
#define NC   256
#define NH   96
#define NW   96
#define NP   9216
#define NCQ  32
#define NKC  6
#define NL   192
#define NV   320          // 256 v-channels + 32 q + 32 k
#define NTOT 73728        // NBAT*NP

typedef __attribute__((ext_vector_type(4))) float  floatx4;
typedef __attribute__((ext_vector_type(8))) short  short8;

// ---------- bf16 helpers (storage only; math fp32) ----------
__device__ __forceinline__ float bf2f(unsigned short h){
  return __uint_as_float(((unsigned)h) << 16);
}
__device__ __forceinline__ unsigned short f2bf(float f){
  unsigned u = __float_as_uint(f);
  u += 0x7FFFu + ((u >> 16) & 1u);
  return (unsigned short)(u >> 16);
}

union F4 { float4 v; float a[4]; };

// ---------- reductions ----------
__device__ __forceinline__ float warpReduceSum(float v){
  #pragma unroll
  for (int m = 32; m; m >>= 1) v += __shfl_xor(v, m);
  return v;
}
__device__ __forceinline__ float warpReduceMax(float v){
  #pragma unroll
  for (int m = 32; m; m >>= 1) v = fmaxf(v, __shfl_xor(v, m));
  return v;
}
__device__ float blockReduceSum(float v){
  __shared__ float lds[8];
  v = warpReduceSum(v);
  int wid = threadIdx.x >> 6, lane = threadIdx.x & 63;
  int nw = blockDim.x >> 6;
  if (lane == 0) lds[wid] = v;
  __syncthreads();
  if (wid == 0){
    v = (lane < nw) ? lds[lane] : 0.f;
    #pragma unroll
    for (int m = 4; m; m >>= 1) v += __shfl_xor(v, m);
  }
  __syncthreads();
  return v;  // valid on thread 0
}
__device__ float blockReduceMax(float v){
  __shared__ float lds[8];
  v = warpReduceMax(v);
  int wid = threadIdx.x >> 6, lane = threadIdx.x & 63;
  int nw = blockDim.x >> 6;
  if (lane == 0) lds[wid] = v;
  __syncthreads();
  if (wid == 0){
    v = (lane < nw) ? lds[lane] : -INFINITY;
    #pragma unroll
    for (int m = 4; m; m >>= 1) v = fmaxf(v, __shfl_xor(v, m));
  }
  __syncthreads();
  return v;
}

// ---------- 1. per-channel stats (float4 vectorized) ----------
__global__ __launch_bounds__(256)
void k_stats(const float* __restrict__ S, const float* __restrict__ T,
             float* __restrict__ s_sum, float* __restrict__ s_sq){
  int blk = blockIdx.x;                 // 2*C*B = 4096
  int t = blk / (NC * NBAT);
  int rem = blk % (NC * NBAT);
  int c = rem / NBAT;
  int n = rem % NBAT;
  const float4* x4 = (const float4*)((t ? T : S) + ((size_t)n * NC + c) * NP);
  float s = 0.f, q = 0.f;
  for (int p = threadIdx.x; p < NP / 4; p += 256){
    F4 f; f.v = x4[p];
    #pragma unroll
    for (int j = 0; j < 4; j++){ s += f.a[j]; q += f.a[j] * f.a[j]; }
  }
  s = blockReduceSum(s);
  q = blockReduceSum(q);
  if (threadIdx.x == 0){
    atomicAdd(&s_sum[t * NC + c], s);
    atomicAdd(&s_sq[t * NC + c], q);
  }
}

__global__ __launch_bounds__(512)
void k_finalize(const float* __restrict__ s_sum, const float* __restrict__ s_sq,
                float* __restrict__ mean, float* __restrict__ inv){
  int i = threadIdx.x;
  if (i < 2 * NC){
    float s = s_sum[i], q = s_sq[i];
    float m = s / (float)NTOT;
    float var = (q - s * m) / (float)(NTOT - 1);
    var = fmaxf(var, 0.f);
    mean[i] = m;
    inv[i] = 1.f / (sqrtf(var) + 1e-6f);
  }
}

// ---------- 2. causal attention ----------
__global__ __launch_bounds__(256)
void k_caM(const float* __restrict__ S, const float* __restrict__ T,
           const float* __restrict__ wcls,
           const float* __restrict__ mean, const float* __restrict__ inv,
           float* __restrict__ smca){
  int pt = blockIdx.x, n = blockIdx.y, t = blockIdx.z;   // (36, 8, 2)
  __shared__ float wsc[NKC * NC];
  __shared__ float shift[NKC];
  for (int idx = threadIdx.x; idx < NKC * NC; idx += 256){
    int c = idx & 255;
    wsc[idx] = wcls[idx] * inv[t * NC + c];
  }
  __syncthreads();
  if (threadIdx.x < NKC){
    float sh = 0.f;
    for (int c = 0; c < NC; c++) sh += wsc[threadIdx.x * NC + c] * mean[t * NC + c];
    shift[threadIdx.x] = sh;
  }
  __syncthreads();
  int p = pt * 256 + threadIdx.x;
  const float* x = (t ? T : S) + (size_t)n * NC * NP + p;
  float acc[NKC];
  #pragma unroll
  for (int k = 0; k < NKC; k++) acc[k] = 0.f;
  for (int c = 0; c < NC; c++){
    float xv = x[(size_t)c * NP];
    #pragma unroll
    for (int k = 0; k < NKC; k++) acc[k] += wsc[k * NC + c] * xv;
  }
  size_t base = ((size_t)(t * NBAT + n) * NKC) * NP + p;
  #pragma unroll
  for (int k = 0; k < NKC; k++) smca[base + (size_t)k * NP] = acc[k] - shift[k];
}

__global__ __launch_bounds__(256)
void k_caSoftmax(float* __restrict__ smca){
  int r = blockIdx.x;                      // 96 rows
  float* row = smca + (size_t)r * NP;
  float m = -INFINITY;
  for (int p = threadIdx.x; p < NP; p += 256) m = fmaxf(m, row[p]);
  m = blockReduceMax(m);
  __shared__ float bm, bs;
  if (threadIdx.x == 0) bm = m;
  __syncthreads();
  m = bm;
  float s = 0.f;
  for (int p = threadIdx.x; p < NP; p += 256) s += expf(row[p] - m);
  s = blockReduceSum(s);
  if (threadIdx.x == 0) bs = 1.f / s;
  __syncthreads();
  float rs = bs;
  for (int p = threadIdx.x; p < NP; p += 256) row[p] = expf(row[p] - m) * rs;
}

// split-K caOut: grid.x = ct(8) + 8*ks(6)
__global__ __launch_bounds__(256)
void k_caOut(const float* __restrict__ S, const float* __restrict__ T,
             const float* __restrict__ smca,
             const float* __restrict__ mean, const float* __restrict__ inv,
             float* __restrict__ ca){
  int ct = blockIdx.x & 7, ks = blockIdx.x >> 3;
  int n = blockIdx.y, t = blockIdx.z;   // (48, 8, 2)
  int c0 = ct * 32;
  __shared__ float xt[32 * 264];
  __shared__ float smt[NKC * 256];
  int cl = threadIdx.x >> 3, pl = threadIdx.x & 7;
  float acc[NKC];
  #pragma unroll
  for (int k = 0; k < NKC; k++) acc[k] = 0.f;
  const float* xbase = (t ? T : S) + (size_t)n * NC * NP;
  const float* smbase = smca + (size_t)(t * NBAT + n) * NKC * NP;
  for (int pt = ks * 6; pt < ks * 6 + 6; pt++){
    int p0 = pt * 256;
    for (int idx = threadIdx.x; idx < 32 * 256; idx += 256){
      int r = idx >> 8, p = idx & 255;
      float v = xbase[(size_t)(c0 + r) * NP + p0 + p];
      xt[r * 264 + p] = (v - mean[t * NC + c0 + r]) * inv[t * NC + c0 + r];
    }
    for (int idx = threadIdx.x; idx < NKC * 256; idx += 256){
      int k = idx >> 8, p = idx & 255;
      smt[idx] = smbase[(size_t)k * NP + p0 + p];
    }
    __syncthreads();
    for (int j = 0; j < 32; j++){
      float xv = xt[cl * 264 + pl + 8 * j];
      #pragma unroll
      for (int k = 0; k < NKC; k++) acc[k] += smt[k * 256 + pl + 8 * j] * xv;
    }
    __syncthreads();
  }
  #pragma unroll
  for (int k = 0; k < NKC; k++){
    float v = acc[k];
    v += __shfl_xor(v, 1); v += __shfl_xor(v, 2); v += __shfl_xor(v, 4);
    if (pl == 0) atomicAdd(&ca[((size_t)(t * NBAT + n) * NKC + k) * NC + c0 + cl], v);
  }
}

__global__ __launch_bounds__(256)
void k_caLoss(const float* __restrict__ ca, float* __restrict__ out){
  int i = blockIdx.x * 256 + threadIdx.x;   // 12288 total
  float d = 0.f;
  if (i < NBAT * NKC * NC) d = ca[(size_t)NBAT * NKC * NC + i] - ca[i];
  float ss = blockReduceSum(d * d);
  if (threadIdx.x == 0) atomicAdd(out, ss * (0.0005f / 8.0f));
}

// ---------- 3. stage normalized x as bf16 XN[p][c] for T (ts=0) and S (ts=1) ----------
__global__ __launch_bounds__(256)
void k_xn(const float* __restrict__ S, const float* __restrict__ T, int bg,
          const float* __restrict__ mean, const float* __restrict__ inv,
          unsigned short* __restrict__ XNT, unsigned short* __restrict__ XNS){
  int pt = blockIdx.x, ct = blockIdx.y, ts = blockIdx.z;  // (144, 4, 2)
  int t = ts ? 0 : 1;
  const float* x0 = ts ? S : T;
  unsigned short* XN = ts ? XNS : XNT;
  int p0 = pt * 64, c0 = ct * 64;
  __shared__ float tile[64 * 65];
  const float* x = x0 + ((size_t)bg * NC + c0) * NP + p0;
  #pragma unroll
  for (int i = 0; i < 4; i++){
    int idx = threadIdx.x + i * 256;       // 64 c-rows x 16 float4 groups
    int r = idx >> 4, g = (idx & 15) * 4;
    F4 f; f.v = *(const float4*)(x + (size_t)r * NP + g);
    float m = mean[t * NC + c0 + r], iv = inv[t * NC + c0 + r];
    #pragma unroll
    for (int j = 0; j < 4; j++) tile[(g + j) * 65 + r] = (f.a[j] - m) * iv;
  }
  __syncthreads();
  #pragma unroll
  for (int i = 0; i < 4; i++){
    int idx = threadIdx.x + i * 256;       // 64 p-rows x 16 groups of 4c
    int p = idx >> 4, g = (idx & 15) * 4;
    unsigned lo = (unsigned)f2bf(tile[p * 65 + g + 0]) | ((unsigned)f2bf(tile[p * 65 + g + 1]) << 16);
    unsigned hi = (unsigned)f2bf(tile[p * 65 + g + 2]) | ((unsigned)f2bf(tile[p * 65 + g + 3]) << 16);
    uint2 u; u.x = lo; u.y = hi;
    *(uint2*)(XN + ((size_t)(p0 + p)) * NC + c0 + g) = u;
  }
}

// ---------- 3b. pre-convert W (v|q|k) to bf16 Wb[320][256], once per launch ----------
__global__ __launch_bounds__(256)
void k_wconv(const float* __restrict__ wv, const float* __restrict__ wq,
             const float* __restrict__ wk, unsigned short* __restrict__ Wb){
  int n = blockIdx.x;         // 320
  const float* src = (n < 256) ? (wv + (size_t)n * NC)
                   : (n < 288) ? (wq + (size_t)(n - 256) * NC)
                               : (wk + (size_t)(n - 288) * NC);
  Wb[(size_t)n * NC + threadIdx.x] = f2bf(src[threadIdx.x]);
}

// ---------- 4. MFMA GEMM: XN[p x 256] @ Wb^T -> VT1[c][p] + q,k [p][cq] ----------
__global__ __launch_bounds__(256)
void k_v(const unsigned short* __restrict__ XNT, const unsigned short* __restrict__ XNS,
         const unsigned short* __restrict__ Wb,
         const float* __restrict__ bv, const float* __restrict__ bq,
         const float* __restrict__ bk,
         unsigned short* __restrict__ VT1T, unsigned short* __restrict__ VT1S,
         unsigned short* __restrict__ qT, unsigned short* __restrict__ kT,
         unsigned short* __restrict__ qS, unsigned short* __restrict__ kS){
  int pt = blockIdx.x, ts = blockIdx.y;   // (144, 2)
  const unsigned short* XN = ts ? XNS : XNT;
  unsigned short* VT1 = ts ? VT1S : VT1T;
  unsigned short* qb  = ts ? qS : qT;
  unsigned short* kb  = ts ? kS : kT;
  int p0 = pt * 64;
  __shared__ unsigned short Wl[NV * 40];  // stride 40 shorts (80B, 16B-aligned rows)
  int lane = threadIdx.x & 63;
  int wid = threadIdx.x >> 6;
  int col = lane & 15, quad = lane >> 4;
  const unsigned short* xnb = XN + (size_t)(p0 + wid * 16 + col) * NC;
  floatx4 acc[20];
  #pragma unroll
  for (int nt = 0; nt < 20; nt++) acc[nt] = (floatx4){0.f, 0.f, 0.f, 0.f};

  int ci_n[5], ci_k8[5];
  #pragma unroll
  for (int i = 0; i < 5; i++){ int ci = i * 256 + threadIdx.x; ci_n[i] = ci >> 2; ci_k8[i] = (ci & 3) * 8; }

  short8 w[5];
  #pragma unroll
  for (int i = 0; i < 5; i++)
    w[i] = *(const short8*)(Wb + (size_t)ci_n[i] * NC + ci_k8[i]);

  for (int ks = 0; ks < 8; ks++){
    if (ks) __syncthreads();              // previous slice's reads done
    #pragma unroll
    for (int i = 0; i < 5; i++)
      *(short8*)(Wl + ci_n[i] * 40 + ci_k8[i]) = w[i];
    __syncthreads();
    if (ks < 7){
      int k0n = (ks + 1) * 32;
      #pragma unroll
      for (int i = 0; i < 5; i++)
        w[i] = *(const short8*)(Wb + (size_t)ci_n[i] * NC + k0n + ci_k8[i]);
    }
    short8 a = *(const short8*)(xnb + ks * 32 + quad * 8);
    #pragma unroll
    for (int nt = 0; nt < 20; nt++){
      short8 b = *(const short8*)(Wl + (nt * 16 + col) * 40 + quad * 8);
      acc[nt] = __builtin_amdgcn_mfma_f32_16x16x32_bf16(a, b, acc[nt], 0, 0, 0);
    }
  }

  int prow0 = p0 + wid * 16 + quad * 4;
  #pragma unroll
  for (int nt = 0; nt < 16; nt++){
    int c = nt * 16 + col;
    float bias = bv[c];
    uint2 u;
    u.x = (unsigned)f2bf(acc[nt][0] + bias) | ((unsigned)f2bf(acc[nt][1] + bias) << 16);
    u.y = (unsigned)f2bf(acc[nt][2] + bias) | ((unsigned)f2bf(acc[nt][3] + bias) << 16);
    *(uint2*)(VT1 + (size_t)c * NP + prow0) = u;
  }
  #pragma unroll
  for (int nt = 16; nt < 18; nt++){
    int c = (nt - 16) * 16 + col;
    float bias = bq[c];
    #pragma unroll
    for (int i = 0; i < 4; i++)
      qb[((size_t)(prow0 + i)) * NCQ + c] = f2bf(acc[nt][i] + bias);
  }
  #pragma unroll
  for (int nt = 18; nt < 20; nt++){
    int c = (nt - 18) * 16 + col;
    float bias = bk[c];
    #pragma unroll
    for (int i = 0; i < 4; i++)
      kb[((size_t)(prow0 + i)) * NCQ + c] = f2bf(acc[nt][i] + bias);
  }
}

// ---------- 4b. spatial transpose: VT2[c][w*96+h] = VT1[c][h*96+w] ----------
__global__ __launch_bounds__(256)
void k_vt(const unsigned short* __restrict__ VT1T, const unsigned short* __restrict__ VT1S,
          unsigned short* __restrict__ VT2T, unsigned short* __restrict__ VT2S){
  int c = blockIdx.x, ts = blockIdx.y;    // (256, 2)
  const unsigned short* VT1 = ts ? VT1S : VT1T;
  unsigned short* VT2 = ts ? VT2S : VT2T;
  __shared__ unsigned short tile[96 * 104];  // [w][h], stride 104 (16B-aligned rows)
  size_t base = (size_t)c * NP;
  for (int idx = threadIdx.x; idx < 1152; idx += 256){
    int h = idx / 12, g = idx % 12;
    short8 v = *(const short8*)(VT1 + base + h * 96 + g * 8);
    #pragma unroll
    for (int kk = 0; kk < 8; kk++) tile[(g * 8 + kk) * 104 + h] = ((unsigned short*)&v)[kk];
  }
  __syncthreads();
  for (int idx = threadIdx.x; idx < 1152; idx += 256){
    int w = idx / 12, g = idx % 12;
    short8 v = *(const short8*)(tile + w * 104 + g * 8);
    *(short8*)(VT2 + base + w * 96 + g * 8) = v;
  }
}

// ---------- 5+6. eH (z=0, diag masked) / eW (z=1) scores, T/S via y ----------
__global__ __launch_bounds__(256)
void k_e(const unsigned short* __restrict__ qT, const unsigned short* __restrict__ kT,
         const unsigned short* __restrict__ qS, const unsigned short* __restrict__ kS,
         unsigned short* __restrict__ attT, unsigned short* __restrict__ attS){
  int x = blockIdx.x, ts = blockIdx.y, which = blockIdx.z;   // (96, 2, 2)
  const unsigned short* qb = ts ? qS : qT;
  const unsigned short* kb = ts ? kS : kT;
  unsigned short* att = ts ? attS : attT;
  int lane = threadIdx.x & 63, wid = threadIdx.x >> 6;
  int col = lane & 15, quad = lane >> 4;
  int mi0 = (wid & 1) * 3, ni0 = (wid >> 1) * 3;
  short8 a[3], b[3];
  if (which == 0){            // eH: fixed w=x, p = i*96 + x
    #pragma unroll
    for (int m = 0; m < 3; m++)
      a[m] = *(const short8*)(qb + ((size_t)(((mi0 + m) * 16 + col) * 96 + x)) * NCQ + quad * 8);
    #pragma unroll
    for (int n = 0; n < 3; n++)
      b[n] = *(const short8*)(kb + ((size_t)(((ni0 + n) * 16 + col) * 96 + x)) * NCQ + quad * 8);
  } else {                    // eW: fixed h=x, p = x*96 + i
    #pragma unroll
    for (int m = 0; m < 3; m++)
      a[m] = *(const short8*)(qb + ((size_t)(x * 96 + (mi0 + m) * 16 + col)) * NCQ + quad * 8);
    #pragma unroll
    for (int n = 0; n < 3; n++)
      b[n] = *(const short8*)(kb + ((size_t)(x * 96 + (ni0 + n) * 16 + col)) * NCQ + quad * 8);
  }
  floatx4 acc[3][3];
  #pragma unroll
  for (int m = 0; m < 3; m++)
    #pragma unroll
    for (int n = 0; n < 3; n++){
      acc[m][n] = (floatx4){0.f, 0.f, 0.f, 0.f};
      acc[m][n] = __builtin_amdgcn_mfma_f32_16x16x32_bf16(a[m], b[n], acc[m][n], 0, 0, 0);
    }
  #pragma unroll
  for (int m = 0; m < 3; m++)
    #pragma unroll
    for (int n = 0; n < 3; n++){
      int j = (ni0 + n) * 16 + col;
      #pragma unroll
      for (int r = 0; r < 4; r++){
        int i = (mi0 + m) * 16 + quad * 4 + r;
        int p = which ? (x * 96 + i) : (i * 96 + x);
        float v = (!which && j == i) ? -INFINITY : acc[m][n][r];
        att[(size_t)p * NL + (which ? 96 + j : j)] = f2bf(v);
      }
    }
}

// ---------- 7. softmax over 192 per query (T rows then S rows) ----------
__global__ __launch_bounds__(256)
void k_attSoftmax(unsigned short* __restrict__ attT, unsigned short* __restrict__ attS){
  int q = blockIdx.x * 4 + (threadIdx.x >> 6);    // 0 .. 2*NP-1
  int lane = threadIdx.x & 63;
  unsigned short* row = (q < NP) ? (attT + (size_t)q * NL)
                                 : (attS + (size_t)(q - NP) * NL);
  float e0 = bf2f(row[lane]);
  float e1 = bf2f(row[64 + lane]);
  float e2 = bf2f(row[128 + lane]);
  float m = fmaxf(e0, fmaxf(e1, e2));
  m = warpReduceMax(m);
  float x0 = expf(e0 - m), x1 = expf(e1 - m), x2 = expf(e2 - m);
  float s = warpReduceSum(x0 + x1 + x2);
  float rs = 1.f / s;
  row[lane]       = f2bf(x0 * rs);
  row[64 + lane]  = f2bf(x1 * rs);
  row[128 + lane] = f2bf(x2 * rs);
}

// ---------- 8. outH (MFMA, T/S via y, channel-split z): OH[i*96+w][c] ----------
__global__ __launch_bounds__(256)
void k_outH(const unsigned short* __restrict__ VT2T, const unsigned short* __restrict__ VT2S,
            const unsigned short* __restrict__ attT, const unsigned short* __restrict__ attS,
            unsigned short* __restrict__ OHT, unsigned short* __restrict__ OHS){
  int w = blockIdx.x, ts = blockIdx.y, cs = blockIdx.z;    // (96, 2, 4)
  const unsigned short* VT2 = ts ? VT2S : VT2T;
  const unsigned short* att = ts ? attS : attT;
  unsigned short* OH = ts ? OHS : OHT;
  int lane = threadIdx.x & 63, wid = threadIdx.x >> 6;
  int col = lane & 15, quad = lane >> 4;
  int c = cs * 64 + wid * 16 + col;
  floatx4 acc[6];
  #pragma unroll
  for (int m = 0; m < 6; m++) acc[m] = (floatx4){0.f, 0.f, 0.f, 0.f};
  #pragma unroll
  for (int ks = 0; ks < 3; ks++){
    int k0 = ks * 32 + quad * 8;
    short8 a[6], b;
    #pragma unroll
    for (int m = 0; m < 6; m++)
      a[m] = *(const short8*)(att + ((size_t)((m * 16 + col) * 96 + w)) * NL + k0);
    b = *(const short8*)(VT2 + (size_t)c * NP + w * 96 + k0);
    #pragma unroll
    for (int m = 0; m < 6; m++)
      acc[m] = __builtin_amdgcn_mfma_f32_16x16x32_bf16(a[m], b, acc[m], 0, 0, 0);
  }
  #pragma unroll
  for (int m = 0; m < 6; m++){
    #pragma unroll
    for (int r = 0; r < 4; r++){
      int i = m * 16 + quad * 4 + r;
      OH[((size_t)(i * 96 + w)) * NC + c] = f2bf(acc[m][r]);
    }
  }
}

// ---------- 9. combined outW for T and S + fused loss (no Ot buffer) ----------
__global__ __launch_bounds__(256)
void k_outWL(const unsigned short* __restrict__ VT1T, const unsigned short* __restrict__ attT,
             const unsigned short* __restrict__ OHT,
             const unsigned short* __restrict__ VT1S, const unsigned short* __restrict__ attS,
             const unsigned short* __restrict__ OHS,
             const float* __restrict__ predsS, const float* __restrict__ predsT,
             const float* __restrict__ mean, const float* __restrict__ inv,
             const float* __restrict__ gamma, int bg,
             float* __restrict__ out){
  int h = blockIdx.x, cs = blockIdx.y;    // (96, 4)
  int lane = threadIdx.x & 63, wid = threadIdx.x >> 6;
  int col = lane & 15, quad = lane >> 4;
  int cl = wid * 16 + col;            // local channel 0..63
  int c  = cs * 64 + cl;

  __shared__ unsigned short ohT[96 * 72];   // [i][cl], stride 72
  __shared__ unsigned short ohS[96 * 72];

  // stage both OH slabs (96 rows x 128B each) cooperatively
  #pragma unroll
  for (int k = 0; k < 3; k++){
    int g = threadIdx.x + k * 256;
    int i = g >> 3, cc = (g & 7) * 8;
    size_t ga = ((size_t)(h * 96 + i)) * NC + cs * 64 + cc;
    *(short8*)(ohT + i * 72 + cc) = *(const short8*)(OHT + ga);
    *(short8*)(ohS + i * 72 + cc) = *(const short8*)(OHS + ga);
  }
  __syncthreads();

  floatx4 accT[6], accS[6];
  #pragma unroll
  for (int m = 0; m < 6; m++){
    accT[m] = (floatx4){0.f, 0.f, 0.f, 0.f};
    accS[m] = (floatx4){0.f, 0.f, 0.f, 0.f};
  }
  #pragma unroll
  for (int ks = 0; ks < 3; ks++){
    int k0 = ks * 32 + quad * 8;
    short8 a[6], b;
    #pragma unroll
    for (int m = 0; m < 6; m++)
      a[m] = *(const short8*)(attT + ((size_t)(h * 96 + m * 16 + col)) * NL + 96 + k0);
    b = *(const short8*)(VT1T + (size_t)c * NP + h * 96 + k0);
    #pragma unroll
    for (int m = 0; m < 6; m++)
      accT[m] = __builtin_amdgcn_mfma_f32_16x16x32_bf16(a[m], b, accT[m], 0, 0, 0);
  }
  #pragma unroll
  for (int ks = 0; ks < 3; ks++){
    int k0 = ks * 32 + quad * 8;
    short8 a[6], b;
    #pragma unroll
    for (int m = 0; m < 6; m++)
      a[m] = *(const short8*)(attS + ((size_t)(h * 96 + m * 16 + col)) * NL + 96 + k0);
    b = *(const short8*)(VT1S + (size_t)c * NP + h * 96 + k0);
    #pragma unroll
    for (int m = 0; m < 6; m++)
      accS[m] = __builtin_amdgcn_mfma_f32_16x16x32_bf16(a[m], b, accS[m], 0, 0, 0);
  }

  float g = gamma[0];
  float ss = 0.f;
  float mS = mean[c],      iS = inv[c];
  float mT = mean[NC + c], iT = inv[NC + c];
  const float* tp = predsT + ((size_t)bg * NC + c) * NP + h * 96;
  const float* sp = predsS + ((size_t)bg * NC + c) * NP + h * 96;
  #pragma unroll
  for (int m = 0; m < 6; m++){
    int i0 = m * 16 + quad * 4;
    F4 tv, sv;
    tv.v = *(const float4*)(tp + i0);
    sv.v = *(const float4*)(sp + i0);
    #pragma unroll
    for (int r = 0; r < 4; r++){
      int i = i0 + r;
      float oT = accT[m][r] + bf2f(ohT[i * 72 + cl]);
      float oS = accS[m][r] + bf2f(ohS[i * 72 + cl]);
      float dn = (tv.a[r] - mT) * iT - (sv.a[r] - mS) * iS;
      float d = g * (oT - oS) + dn;
      ss += d * d;
    }
  }
  ss = blockReduceSum(ss);
  if (threadIdx.x == 0) atomicAdd(out, ss * (1e-5f / 8.0f));
}

// ---------- host ----------
extern "C" void kernel_launch(void* const* d_in, const int* in_sizes, int n_in,
                              void* d_out, int out_size, void* d_ws, size_t ws_size,
                              hipStream_t stream){
  (void)in_sizes; (void)n_in; (void)out_size; (void)ws_size;
  const float* S    = (const float*)d_in[0];
  const float* T    = (const float*)d_in[1];
  const float* wcls = (const float*)d_in[2];
  const float* wq   = (const float*)d_in[3];
  const float* bq   = (const float*)d_in[4];
  const float* wk   = (const float*)d_in[5];
  const float* bk   = (const float*)d_in[6];
  const float* wv   = (const float*)d_in[7];
  const float* bv   = (const float*)d_in[8];
  const float* gamma= (const float*)d_in[9];
  float* out = (float*)d_out;

  char* base = (char*)d_ws;
  size_t off = 0;
  auto alloc = [&](size_t b){ size_t o = off; off += (b + 255) & ~(size_t)255; return o; };
  size_t o_ssum = alloc(2 * NC * 4);
  size_t o_ssq  = alloc(2 * NC * 4);
  size_t o_mean = alloc(2 * NC * 4);
  size_t o_inv  = alloc(2 * NC * 4);
  size_t o_wb   = alloc((size_t)NV * NC * 2);
  size_t o_ca   = alloc((size_t)2 * NBAT * NKC * NC * 4);
  size_t o_smca = alloc((size_t)2 * NBAT * NKC * NP * 4);

  const size_t PB  = (size_t)NP * NC * 2;     // 4.72 MB bf16 plane
  const size_t ATT = (size_t)NP * NL * 2;     // 3.54 MB
  const size_t QB  = (size_t)NP * NCQ * 2;    // 0.59 MB
  size_t o_a  = alloc(PB);     // XN_T, later OH_T
  size_t o_b  = alloc(PB);     // VT1_T
  size_t o_c  = alloc(PB);     // XN_S, later VT2_T
  size_t o_d  = alloc(PB);     // VT1_S
  size_t o_e  = alloc(PB);     // VT2_S
  size_t o_f  = alloc(PB);     // OH_S
  size_t o_gT = alloc(ATT);    // att_T
  size_t o_gS = alloc(ATT);    // att_S
  size_t o_qT = alloc(QB);
  size_t o_kT = alloc(QB);
  size_t o_qS = alloc(QB);
  size_t o_kS = alloc(QB);

  float* ssum = (float*)(base + o_ssum);
  float* ssq  = (float*)(base + o_ssq);
  float* mean = (float*)(base + o_mean);
  float* inv  = (float*)(base + o_inv);
  float* ca   = (float*)(base + o_ca);
  float* smca = (float*)(base + o_smca);
  unsigned short* Wb  = (unsigned short*)(base + o_wb);
  unsigned short* A   = (unsigned short*)(base + o_a);
  unsigned short* B   = (unsigned short*)(base + o_b);
  unsigned short* C   = (unsigned short*)(base + o_c);
  unsigned short* D   = (unsigned short*)(base + o_d);
  unsigned short* E   = (unsigned short*)(base + o_e);
  unsigned short* F   = (unsigned short*)(base + o_f);
  unsigned short* attT= (unsigned short*)(base + o_gT);
  unsigned short* attS= (unsigned short*)(base + o_gS);
  unsigned short* qT  = (unsigned short*)(base + o_qT);
  unsigned short* kT  = (unsigned short*)(base + o_kT);
  unsigned short* qS  = (unsigned short*)(base + o_qS);
  unsigned short* kS  = (unsigned short*)(base + o_kS);

  hipMemsetAsync(d_out, 0, 4, stream);
  hipMemsetAsync(base + o_ssum, 0, 4096, stream);
  hipMemsetAsync(base + o_ca, 0, (size_t)2 * NBAT * NKC * NC * 4, stream);

  k_stats<<<dim3(2 * NC * NBAT), 256, 0, stream>>>(S, T, ssum, ssq);
  k_finalize<<<1, 512, 0, stream>>>(ssum, ssq, mean, inv);
  k_wconv<<<dim3(NV), 256, 0, stream>>>(wv, wq, wk, Wb);

  // causal attention (both tensors, full batch)
  k_caM<<<dim3(36, NBAT, 2), 256, 0, stream>>>(S, T, wcls, mean, inv, smca);
  k_caSoftmax<<<dim3(2 * NBAT * NKC), 256, 0, stream>>>(smca);
  k_caOut<<<dim3(48, NBAT, 2), 256, 0, stream>>>(S, T, smca, mean, inv, ca);
  k_caLoss<<<dim3(48), 256, 0, stream>>>(ca, out);

  // ccnet: per batch, T and S pipelines in one super-step; loss fused in k_outWL
  for (int bg = 0; bg < NBAT; bg++){
    k_xn<<<dim3(144, 4, 2), 256, 0, stream>>>(S, T, bg, mean, inv, A, C);
    k_v<<<dim3(144, 2), 256, 0, stream>>>(A, C, Wb, bv, bq, bk, B, D, qT, kT, qS, kS);
    k_vt<<<dim3(256, 2), 256, 0, stream>>>(B, D, C /*VT2_T*/, E /*VT2_S*/);
    k_e<<<dim3(96, 2, 2), 256, 0, stream>>>(qT, kT, qS, kS, attT, attS);
    k_attSoftmax<<<dim3(2 * NP / 4), 256, 0, stream>>>(attT, attS);
    k_outH<<<dim3(96, 2, 4), 256, 0, stream>>>(C, E, attT, attS, A /*OH_T*/, F /*OH_S*/);
    k_outWL<<<dim3(96, 4), 256, 0, stream>>>(B, attT, A, D, attS, F, S, T, mean, inv,
                                             gamma, bg, out);
  }
}

// Round 5
// 647.474 us; speedup vs baseline: 1.3269x; 1.3269x over previous
//
#include <hip/hip_runtime.h>
#include <math.h>

#define NBAT 8
#define NC   256
#define NH   96
#define NW   96
#define NP   9216
#define NCQ  32
#define NKC  6
#define NL   192
#define NV   320          // 256 v-channels + 32 q + 32 k
#define NTOT 73728        // NBAT*NP

typedef __attribute__((ext_vector_type(4))) float  floatx4;
typedef __attribute__((ext_vector_type(8))) short  short8;

// ---------- bf16 helpers (storage only; math fp32) ----------
__device__ __forceinline__ float bf2f(unsigned short h){
  return __uint_as_float(((unsigned)h) << 16);
}
__device__ __forceinline__ unsigned short f2bf(float f){
  unsigned u = __float_as_uint(f);
  u += 0x7FFFu + ((u >> 16) & 1u);
  return (unsigned short)(u >> 16);
}

union F4 { float4 v; float a[4]; };

// ---------- reductions ----------
__device__ __forceinline__ float warpReduceSum(float v){
  #pragma unroll
  for (int m = 32; m; m >>= 1) v += __shfl_xor(v, m);
  return v;
}
__device__ __forceinline__ float warpReduceMax(float v){
  #pragma unroll
  for (int m = 32; m; m >>= 1) v = fmaxf(v, __shfl_xor(v, m));
  return v;
}
__device__ float blockReduceSum(float v){
  __shared__ float lds[8];
  v = warpReduceSum(v);
  int wid = threadIdx.x >> 6, lane = threadIdx.x & 63;
  int nw = blockDim.x >> 6;
  if (lane == 0) lds[wid] = v;
  __syncthreads();
  if (wid == 0){
    v = (lane < nw) ? lds[lane] : 0.f;
    #pragma unroll
    for (int m = 4; m; m >>= 1) v += __shfl_xor(v, m);
  }
  __syncthreads();
  return v;  // valid on thread 0
}
__device__ float blockReduceMax(float v){
  __shared__ float lds[8];
  v = warpReduceMax(v);
  int wid = threadIdx.x >> 6, lane = threadIdx.x & 63;
  int nw = blockDim.x >> 6;
  if (lane == 0) lds[wid] = v;
  __syncthreads();
  if (wid == 0){
    v = (lane < nw) ? lds[lane] : -INFINITY;
    #pragma unroll
    for (int m = 4; m; m >>= 1) v = fmaxf(v, __shfl_xor(v, m));
  }
  __syncthreads();
  return v;
}

// ---------- 1. per-channel stats (float4 vectorized) ----------
__global__ __launch_bounds__(256)
void k_stats(const float* __restrict__ S, const float* __restrict__ T,
             float* __restrict__ s_sum, float* __restrict__ s_sq){
  int blk = blockIdx.x;                 // 2*C*B = 4096
  int t = blk / (NC * NBAT);
  int rem = blk % (NC * NBAT);
  int c = rem / NBAT;
  int n = rem % NBAT;
  const float4* x4 = (const float4*)((t ? T : S) + ((size_t)n * NC + c) * NP);
  float s = 0.f, q = 0.f;
  for (int p = threadIdx.x; p < NP / 4; p += 256){
    F4 f; f.v = x4[p];
    #pragma unroll
    for (int j = 0; j < 4; j++){ s += f.a[j]; q += f.a[j] * f.a[j]; }
  }
  s = blockReduceSum(s);
  q = blockReduceSum(q);
  if (threadIdx.x == 0){
    atomicAdd(&s_sum[t * NC + c], s);
    atomicAdd(&s_sq[t * NC + c], q);
  }
}

__global__ __launch_bounds__(512)
void k_finalize(const float* __restrict__ s_sum, const float* __restrict__ s_sq,
                float* __restrict__ mean, float* __restrict__ inv){
  int i = threadIdx.x;
  if (i < 2 * NC){
    float s = s_sum[i], q = s_sq[i];
    float m = s / (float)NTOT;
    float var = (q - s * m) / (float)(NTOT - 1);
    var = fmaxf(var, 0.f);
    mean[i] = m;
    inv[i] = 1.f / (sqrtf(var) + 1e-6f);
  }
}

// ---------- 2. stage normalized x as bf16 XN[bb][p][c]; ts=0 -> T, ts=1 -> S ----------
__global__ __launch_bounds__(256)
void k_xn(const float* __restrict__ S, const float* __restrict__ T, int b0,
          const float* __restrict__ mean, const float* __restrict__ inv,
          unsigned short* __restrict__ XNT, unsigned short* __restrict__ XNS){
  int pt = blockIdx.x, ct = blockIdx.y;                   // (144, 4, 2*NB)
  int bb = blockIdx.z >> 1, ts = blockIdx.z & 1;
  int t = ts ? 0 : 1;
  const float* x0 = ts ? S : T;
  unsigned short* XN = (ts ? XNS : XNT) + (size_t)bb * NP * NC;
  int bg = b0 + bb;
  int p0 = pt * 64, c0 = ct * 64;
  __shared__ float tile[64 * 65];
  const float* x = x0 + ((size_t)bg * NC + c0) * NP + p0;
  #pragma unroll
  for (int i = 0; i < 4; i++){
    int idx = threadIdx.x + i * 256;       // 64 c-rows x 16 float4 groups
    int r = idx >> 4, g = (idx & 15) * 4;
    F4 f; f.v = *(const float4*)(x + (size_t)r * NP + g);
    float m = mean[t * NC + c0 + r], iv = inv[t * NC + c0 + r];
    #pragma unroll
    for (int j = 0; j < 4; j++) tile[(g + j) * 65 + r] = (f.a[j] - m) * iv;
  }
  __syncthreads();
  #pragma unroll
  for (int i = 0; i < 4; i++){
    int idx = threadIdx.x + i * 256;       // 64 p-rows x 16 groups of 4c
    int p = idx >> 4, g = (idx & 15) * 4;
    unsigned lo = (unsigned)f2bf(tile[p * 65 + g + 0]) | ((unsigned)f2bf(tile[p * 65 + g + 1]) << 16);
    unsigned hi = (unsigned)f2bf(tile[p * 65 + g + 2]) | ((unsigned)f2bf(tile[p * 65 + g + 3]) << 16);
    uint2 u; u.x = lo; u.y = hi;
    *(uint2*)(XN + ((size_t)(p0 + p)) * NC + c0 + g) = u;
  }
}

// ---------- 3. causal attention from XN (bf16) ----------
// M[k][p] = sum_c wcls[k][c] * xn[p][c]   (xn already normalized; no shift needed)
__global__ __launch_bounds__(256)
void k_caM(const unsigned short* __restrict__ XNT, const unsigned short* __restrict__ XNS,
           const float* __restrict__ wcls, int b0,
           float* __restrict__ smca){
  int pt = blockIdx.x, bb = blockIdx.y, ts = blockIdx.z;   // (36, NB, 2)
  int t = ts ? 0 : 1;
  const unsigned short* XN = (ts ? XNS : XNT) + (size_t)bb * NP * NC;
  __shared__ float wcf[NKC * NC];
  for (int idx = threadIdx.x; idx < NKC * NC; idx += 256) wcf[idx] = wcls[idx];
  __syncthreads();
  int p = pt * 256 + threadIdx.x;
  const unsigned short* row = XN + (size_t)p * NC;
  float acc[NKC];
  #pragma unroll
  for (int k = 0; k < NKC; k++) acc[k] = 0.f;
  for (int c = 0; c < NC; c += 8){
    short8 v = *(const short8*)(row + c);
    #pragma unroll
    for (int j = 0; j < 8; j++){
      float xv = bf2f((unsigned short)v[j]);
      #pragma unroll
      for (int k = 0; k < NKC; k++) acc[k] += wcf[k * NC + c + j] * xv;
    }
  }
  size_t base = ((size_t)(t * NBAT + b0 + bb) * NKC) * NP + p;
  #pragma unroll
  for (int k = 0; k < NKC; k++) smca[base + (size_t)k * NP] = acc[k];
}

__global__ __launch_bounds__(256)
void k_caSoftmax(float* __restrict__ smca, int b0){
  int r = blockIdx.x;                        // 2*NB*NKC rows
  int bb = r / (2 * NKC);
  int rem = r % (2 * NKC);
  int ts = rem / NKC, k = rem % NKC;
  int t = ts ? 0 : 1;
  float* row = smca + ((size_t)(t * NBAT + b0 + bb) * NKC + k) * NP;
  float m = -INFINITY;
  for (int p = threadIdx.x; p < NP; p += 256) m = fmaxf(m, row[p]);
  m = blockReduceMax(m);
  __shared__ float bm, bs;
  if (threadIdx.x == 0) bm = m;
  __syncthreads();
  m = bm;
  float s = 0.f;
  for (int p = threadIdx.x; p < NP; p += 256) s += expf(row[p] - m);
  s = blockReduceSum(s);
  if (threadIdx.x == 0) bs = 1.f / s;
  __syncthreads();
  float rs = bs;
  for (int p = threadIdx.x; p < NP; p += 256) row[p] = expf(row[p] - m) * rs;
}

// ca[k][c] += sum_p sm[k][p] * xn[p][c]   (split over 36 p-tiles, atomics)
__global__ __launch_bounds__(256)
void k_caOut(const unsigned short* __restrict__ XNT, const unsigned short* __restrict__ XNS,
             const float* __restrict__ smca, int b0,
             float* __restrict__ ca){
  int ks = blockIdx.x, bb = blockIdx.y, ts = blockIdx.z;   // (36, NB, 2)
  int t = ts ? 0 : 1;
  const unsigned short* XN = (ts ? XNS : XNT) + (size_t)bb * NP * NC;
  int p0 = ks * 256;
  __shared__ float smt[NKC * 256];
  const float* smbase = smca + (size_t)(t * NBAT + b0 + bb) * NKC * NP;
  for (int idx = threadIdx.x; idx < NKC * 256; idx += 256){
    int k = idx >> 8, pp = idx & 255;
    smt[idx] = smbase[(size_t)k * NP + p0 + pp];
  }
  __syncthreads();
  int c = threadIdx.x;
  float acc[NKC];
  #pragma unroll
  for (int k = 0; k < NKC; k++) acc[k] = 0.f;
  const unsigned short* xp = XN + (size_t)p0 * NC + c;
  for (int pp = 0; pp < 256; pp++){
    float xv = bf2f(xp[(size_t)pp * NC]);
    #pragma unroll
    for (int k = 0; k < NKC; k++) acc[k] += smt[k * 256 + pp] * xv;
  }
  float* cab = ca + ((size_t)(t * NBAT + b0 + bb) * NKC) * NC + c;
  #pragma unroll
  for (int k = 0; k < NKC; k++) atomicAdd(&cab[(size_t)k * NC], acc[k]);
}

__global__ __launch_bounds__(256)
void k_caLoss(const float* __restrict__ ca, float* __restrict__ out){
  int i = blockIdx.x * 256 + threadIdx.x;   // 12288 total
  float d = 0.f;
  if (i < NBAT * NKC * NC) d = ca[(size_t)NBAT * NKC * NC + i] - ca[i];
  float ss = blockReduceSum(d * d);
  if (threadIdx.x == 0) atomicAdd(out, ss * (0.0005f / 8.0f));
}

// ---------- 3b. pre-convert W (v|q|k) to bf16 Wb[320][256], once per launch ----------
__global__ __launch_bounds__(256)
void k_wconv(const float* __restrict__ wv, const float* __restrict__ wq,
             const float* __restrict__ wk, unsigned short* __restrict__ Wb){
  int n = blockIdx.x;         // 320
  const float* src = (n < 256) ? (wv + (size_t)n * NC)
                   : (n < 288) ? (wq + (size_t)(n - 256) * NC)
                               : (wk + (size_t)(n - 288) * NC);
  Wb[(size_t)n * NC + threadIdx.x] = f2bf(src[threadIdx.x]);
}

// ---------- 4. MFMA GEMM: XN[p x 256] @ Wb^T -> VT1[c][p] + q,k [p][cq] ----------
__global__ __launch_bounds__(256)
void k_v(const unsigned short* __restrict__ XNT, const unsigned short* __restrict__ XNS,
         const unsigned short* __restrict__ Wb,
         const float* __restrict__ bv, const float* __restrict__ bq,
         const float* __restrict__ bk,
         unsigned short* __restrict__ VT1T, unsigned short* __restrict__ VT1S,
         unsigned short* __restrict__ qT, unsigned short* __restrict__ kT,
         unsigned short* __restrict__ qS, unsigned short* __restrict__ kS){
  int pt = blockIdx.x;                       // (144, 2*NB)
  int bb = blockIdx.y >> 1, ts = blockIdx.y & 1;
  const unsigned short* XN = (ts ? XNS : XNT) + (size_t)bb * NP * NC;
  unsigned short* VT1 = (ts ? VT1S : VT1T) + (size_t)bb * NP * NC;
  unsigned short* qb  = (ts ? qS : qT) + (size_t)bb * NP * NCQ;
  unsigned short* kb  = (ts ? kS : kT) + (size_t)bb * NP * NCQ;
  int p0 = pt * 64;
  __shared__ unsigned short Wl[NV * 40];  // stride 40 shorts (80B, 16B-aligned rows)
  int lane = threadIdx.x & 63;
  int wid = threadIdx.x >> 6;
  int col = lane & 15, quad = lane >> 4;
  const unsigned short* xnb = XN + (size_t)(p0 + wid * 16 + col) * NC;
  floatx4 acc[20];
  #pragma unroll
  for (int nt = 0; nt < 20; nt++) acc[nt] = (floatx4){0.f, 0.f, 0.f, 0.f};

  int ci_n[5], ci_k8[5];
  #pragma unroll
  for (int i = 0; i < 5; i++){ int ci = i * 256 + threadIdx.x; ci_n[i] = ci >> 2; ci_k8[i] = (ci & 3) * 8; }

  short8 w[5];
  #pragma unroll
  for (int i = 0; i < 5; i++)
    w[i] = *(const short8*)(Wb + (size_t)ci_n[i] * NC + ci_k8[i]);

  for (int ks = 0; ks < 8; ks++){
    if (ks) __syncthreads();              // previous slice's reads done
    #pragma unroll
    for (int i = 0; i < 5; i++)
      *(short8*)(Wl + ci_n[i] * 40 + ci_k8[i]) = w[i];
    __syncthreads();
    if (ks < 7){
      int k0n = (ks + 1) * 32;
      #pragma unroll
      for (int i = 0; i < 5; i++)
        w[i] = *(const short8*)(Wb + (size_t)ci_n[i] * NC + k0n + ci_k8[i]);
    }
    short8 a = *(const short8*)(xnb + ks * 32 + quad * 8);
    #pragma unroll
    for (int nt = 0; nt < 20; nt++){
      short8 b = *(const short8*)(Wl + (nt * 16 + col) * 40 + quad * 8);
      acc[nt] = __builtin_amdgcn_mfma_f32_16x16x32_bf16(a, b, acc[nt], 0, 0, 0);
    }
  }

  int prow0 = p0 + wid * 16 + quad * 4;
  #pragma unroll
  for (int nt = 0; nt < 16; nt++){
    int c = nt * 16 + col;
    float bias = bv[c];
    uint2 u;
    u.x = (unsigned)f2bf(acc[nt][0] + bias) | ((unsigned)f2bf(acc[nt][1] + bias) << 16);
    u.y = (unsigned)f2bf(acc[nt][2] + bias) | ((unsigned)f2bf(acc[nt][3] + bias) << 16);
    *(uint2*)(VT1 + (size_t)c * NP + prow0) = u;
  }
  #pragma unroll
  for (int nt = 16; nt < 18; nt++){
    int c = (nt - 16) * 16 + col;
    float bias = bq[c];
    #pragma unroll
    for (int i = 0; i < 4; i++)
      qb[((size_t)(prow0 + i)) * NCQ + c] = f2bf(acc[nt][i] + bias);
  }
  #pragma unroll
  for (int nt = 18; nt < 20; nt++){
    int c = (nt - 18) * 16 + col;
    float bias = bk[c];
    #pragma unroll
    for (int i = 0; i < 4; i++)
      kb[((size_t)(prow0 + i)) * NCQ + c] = f2bf(acc[nt][i] + bias);
  }
}

// ---------- 4b. spatial transpose: VT2[c][w*96+h] = VT1[c][h*96+w] ----------
__global__ __launch_bounds__(256)
void k_vt(const unsigned short* __restrict__ VT1T, const unsigned short* __restrict__ VT1S,
          unsigned short* __restrict__ VT2T, unsigned short* __restrict__ VT2S){
  int c = blockIdx.x;                        // (256, 2*NB)
  int bb = blockIdx.y >> 1, ts = blockIdx.y & 1;
  const unsigned short* VT1 = (ts ? VT1S : VT1T) + (size_t)bb * NP * NC;
  unsigned short* VT2 = (ts ? VT2S : VT2T) + (size_t)bb * NP * NC;
  __shared__ unsigned short tile[96 * 104];  // [w][h], stride 104 (16B-aligned rows)
  size_t base = (size_t)c * NP;
  for (int idx = threadIdx.x; idx < 1152; idx += 256){
    int h = idx / 12, g = idx % 12;
    short8 v = *(const short8*)(VT1 + base + h * 96 + g * 8);
    #pragma unroll
    for (int kk = 0; kk < 8; kk++) tile[(g * 8 + kk) * 104 + h] = ((unsigned short*)&v)[kk];
  }
  __syncthreads();
  for (int idx = threadIdx.x; idx < 1152; idx += 256){
    int w = idx / 12, g = idx % 12;
    short8 v = *(const short8*)(tile + w * 104 + g * 8);
    *(short8*)(VT2 + base + w * 96 + g * 8) = v;
  }
}

// ---------- 5+6. eH (z=0, diag masked) / eW (z=1) scores ----------
__global__ __launch_bounds__(256)
void k_e(const unsigned short* __restrict__ qT, const unsigned short* __restrict__ kT,
         const unsigned short* __restrict__ qS, const unsigned short* __restrict__ kS,
         unsigned short* __restrict__ attT, unsigned short* __restrict__ attS){
  int x = blockIdx.x, which = blockIdx.z;    // (96, 2*NB, 2)
  int bb = blockIdx.y >> 1, ts = blockIdx.y & 1;
  const unsigned short* qb = (ts ? qS : qT) + (size_t)bb * NP * NCQ;
  const unsigned short* kb = (ts ? kS : kT) + (size_t)bb * NP * NCQ;
  unsigned short* att = (ts ? attS : attT) + (size_t)bb * NP * NL;
  int lane = threadIdx.x & 63, wid = threadIdx.x >> 6;
  int col = lane & 15, quad = lane >> 4;
  int mi0 = (wid & 1) * 3, ni0 = (wid >> 1) * 3;
  short8 a[3], b[3];
  if (which == 0){            // eH: fixed w=x, p = i*96 + x
    #pragma unroll
    for (int m = 0; m < 3; m++)
      a[m] = *(const short8*)(qb + ((size_t)(((mi0 + m) * 16 + col) * 96 + x)) * NCQ + quad * 8);
    #pragma unroll
    for (int n = 0; n < 3; n++)
      b[n] = *(const short8*)(kb + ((size_t)(((ni0 + n) * 16 + col) * 96 + x)) * NCQ + quad * 8);
  } else {                    // eW: fixed h=x, p = x*96 + i
    #pragma unroll
    for (int m = 0; m < 3; m++)
      a[m] = *(const short8*)(qb + ((size_t)(x * 96 + (mi0 + m) * 16 + col)) * NCQ + quad * 8);
    #pragma unroll
    for (int n = 0; n < 3; n++)
      b[n] = *(const short8*)(kb + ((size_t)(x * 96 + (ni0 + n) * 16 + col)) * NCQ + quad * 8);
  }
  floatx4 acc[3][3];
  #pragma unroll
  for (int m = 0; m < 3; m++)
    #pragma unroll
    for (int n = 0; n < 3; n++){
      acc[m][n] = (floatx4){0.f, 0.f, 0.f, 0.f};
      acc[m][n] = __builtin_amdgcn_mfma_f32_16x16x32_bf16(a[m], b[n], acc[m][n], 0, 0, 0);
    }
  #pragma unroll
  for (int m = 0; m < 3; m++)
    #pragma unroll
    for (int n = 0; n < 3; n++){
      int j = (ni0 + n) * 16 + col;
      #pragma unroll
      for (int r = 0; r < 4; r++){
        int i = (mi0 + m) * 16 + quad * 4 + r;
        int p = which ? (x * 96 + i) : (i * 96 + x);
        float v = (!which && j == i) ? -INFINITY : acc[m][n][r];
        att[(size_t)p * NL + (which ? 96 + j : j)] = f2bf(v);
      }
    }
}

// ---------- 7. softmax over 192 per query ----------
__global__ __launch_bounds__(256)
void k_attSoftmax(unsigned short* __restrict__ attT, unsigned short* __restrict__ attS,
                  int nbp){                   // nbp = NB*NP
  int q = blockIdx.x * 4 + (threadIdx.x >> 6);
  int lane = threadIdx.x & 63;
  unsigned short* row = (q < nbp) ? (attT + (size_t)q * NL)
                                  : (attS + (size_t)(q - nbp) * NL);
  float e0 = bf2f(row[lane]);
  float e1 = bf2f(row[64 + lane]);
  float e2 = bf2f(row[128 + lane]);
  float m = fmaxf(e0, fmaxf(e1, e2));
  m = warpReduceMax(m);
  float x0 = expf(e0 - m), x1 = expf(e1 - m), x2 = expf(e2 - m);
  float s = warpReduceSum(x0 + x1 + x2);
  float rs = 1.f / s;
  row[lane]       = f2bf(x0 * rs);
  row[64 + lane]  = f2bf(x1 * rs);
  row[128 + lane] = f2bf(x2 * rs);
}

// ---------- 8. outH (MFMA, channel-split z): OH[i*96+w][c] ----------
__global__ __launch_bounds__(256)
void k_outH(const unsigned short* __restrict__ VT2T, const unsigned short* __restrict__ VT2S,
            const unsigned short* __restrict__ attT, const unsigned short* __restrict__ attS,
            unsigned short* __restrict__ OHT, unsigned short* __restrict__ OHS){
  int w = blockIdx.x, cs = blockIdx.z;       // (96, 2*NB, 4)
  int bb = blockIdx.y >> 1, ts = blockIdx.y & 1;
  const unsigned short* VT2 = (ts ? VT2S : VT2T) + (size_t)bb * NP * NC;
  const unsigned short* att = (ts ? attS : attT) + (size_t)bb * NP * NL;
  unsigned short* OH = (ts ? OHS : OHT) + (size_t)bb * NP * NC;
  int lane = threadIdx.x & 63, wid = threadIdx.x >> 6;
  int col = lane & 15, quad = lane >> 4;
  int c = cs * 64 + wid * 16 + col;
  floatx4 acc[6];
  #pragma unroll
  for (int m = 0; m < 6; m++) acc[m] = (floatx4){0.f, 0.f, 0.f, 0.f};
  #pragma unroll
  for (int ks = 0; ks < 3; ks++){
    int k0 = ks * 32 + quad * 8;
    short8 a[6], b;
    #pragma unroll
    for (int m = 0; m < 6; m++)
      a[m] = *(const short8*)(att + ((size_t)((m * 16 + col) * 96 + w)) * NL + k0);
    b = *(const short8*)(VT2 + (size_t)c * NP + w * 96 + k0);
    #pragma unroll
    for (int m = 0; m < 6; m++)
      acc[m] = __builtin_amdgcn_mfma_f32_16x16x32_bf16(a[m], b, acc[m], 0, 0, 0);
  }
  #pragma unroll
  for (int m = 0; m < 6; m++){
    #pragma unroll
    for (int r = 0; r < 4; r++){
      int i = m * 16 + quad * 4 + r;
      OH[((size_t)(i * 96 + w)) * NC + c] = f2bf(acc[m][r]);
    }
  }
}

// ---------- 9. combined outW(T,S) + fused loss; dn from XN slabs (no preds read) ----------
__global__ __launch_bounds__(256)
void k_outWL(const unsigned short* __restrict__ VT1T, const unsigned short* __restrict__ attT,
             const unsigned short* __restrict__ OHT,
             const unsigned short* __restrict__ VT1S, const unsigned short* __restrict__ attS,
             const unsigned short* __restrict__ OHS,
             const unsigned short* __restrict__ XNT, const unsigned short* __restrict__ XNS,
             const float* __restrict__ gamma,
             float* __restrict__ out){
  int h = blockIdx.x, bb = blockIdx.y, cs = blockIdx.z;    // (96, NB, 4)
  size_t pb = (size_t)bb * NP * NC;
  int lane = threadIdx.x & 63, wid = threadIdx.x >> 6;
  int col = lane & 15, quad = lane >> 4;
  int cl = wid * 16 + col;            // local channel 0..63
  int c  = cs * 64 + cl;

  __shared__ unsigned short ohTl[96 * 72];   // [i][cl], stride 72
  __shared__ unsigned short ohSl[96 * 72];
  __shared__ unsigned short dnl [96 * 72];   // bf16(xnT - xnS)

  // cooperative slab stage: rows h*96+i, 64-channel slice
  #pragma unroll
  for (int k = 0; k < 3; k++){
    int g = threadIdx.x + k * 256;
    int i = g >> 3, cc = (g & 7) * 8;
    size_t ga = pb + ((size_t)(h * 96 + i)) * NC + cs * 64 + cc;
    short8 ot = *(const short8*)(OHT + ga);
    short8 os = *(const short8*)(OHS + ga);
    short8 xt = *(const short8*)(XNT + ga);
    short8 xs = *(const short8*)(XNS + ga);
    short8 dn;
    #pragma unroll
    for (int j = 0; j < 8; j++)
      ((unsigned short*)&dn)[j] = f2bf(bf2f((unsigned short)xt[j]) - bf2f((unsigned short)xs[j]));
    *(short8*)(ohTl + i * 72 + cc) = ot;
    *(short8*)(ohSl + i * 72 + cc) = os;
    *(short8*)(dnl  + i * 72 + cc) = dn;
  }
  __syncthreads();

  floatx4 accT[6], accS[6];
  #pragma unroll
  for (int m = 0; m < 6; m++){
    accT[m] = (floatx4){0.f, 0.f, 0.f, 0.f};
    accS[m] = (floatx4){0.f, 0.f, 0.f, 0.f};
  }
  #pragma unroll
  for (int ks = 0; ks < 3; ks++){
    int k0 = ks * 32 + quad * 8;
    short8 a[6], b;
    #pragma unroll
    for (int m = 0; m < 6; m++)
      a[m] = *(const short8*)(attT + (size_t)bb * NP * NL + ((size_t)(h * 96 + m * 16 + col)) * NL + 96 + k0);
    b = *(const short8*)(VT1T + pb + (size_t)c * NP + h * 96 + k0);
    #pragma unroll
    for (int m = 0; m < 6; m++)
      accT[m] = __builtin_amdgcn_mfma_f32_16x16x32_bf16(a[m], b, accT[m], 0, 0, 0);
  }
  #pragma unroll
  for (int ks = 0; ks < 3; ks++){
    int k0 = ks * 32 + quad * 8;
    short8 a[6], b;
    #pragma unroll
    for (int m = 0; m < 6; m++)
      a[m] = *(const short8*)(attS + (size_t)bb * NP * NL + ((size_t)(h * 96 + m * 16 + col)) * NL + 96 + k0);
    b = *(const short8*)(VT1S + pb + (size_t)c * NP + h * 96 + k0);
    #pragma unroll
    for (int m = 0; m < 6; m++)
      accS[m] = __builtin_amdgcn_mfma_f32_16x16x32_bf16(a[m], b, accS[m], 0, 0, 0);
  }

  float g = gamma[0];
  float ss = 0.f;
  #pragma unroll
  for (int m = 0; m < 6; m++){
    int i0 = m * 16 + quad * 4;
    #pragma unroll
    for (int r = 0; r < 4; r++){
      int i = i0 + r;
      float oT = accT[m][r] + bf2f(ohTl[i * 72 + cl]);
      float oS = accS[m][r] + bf2f(ohSl[i * 72 + cl]);
      float d = g * (oT - oS) + bf2f(dnl[i * 72 + cl]);
      ss += d * d;
    }
  }
  ss = blockReduceSum(ss);
  if (threadIdx.x == 0) atomicAdd(out, ss * (1e-5f / 8.0f));
}

// ---------- host ----------
extern "C" void kernel_launch(void* const* d_in, const int* in_sizes, int n_in,
                              void* d_out, int out_size, void* d_ws, size_t ws_size,
                              hipStream_t stream){
  (void)in_sizes; (void)n_in; (void)out_size;
  const float* S    = (const float*)d_in[0];
  const float* T    = (const float*)d_in[1];
  const float* wcls = (const float*)d_in[2];
  const float* wq   = (const float*)d_in[3];
  const float* bq   = (const float*)d_in[4];
  const float* wk   = (const float*)d_in[5];
  const float* bk   = (const float*)d_in[6];
  const float* wv   = (const float*)d_in[7];
  const float* bv   = (const float*)d_in[8];
  const float* gamma= (const float*)d_in[9];
  float* out = (float*)d_out;

  char* base = (char*)d_ws;
  size_t off = 0;
  auto alloc = [&](size_t b){ size_t o = off; off += (b + 255) & ~(size_t)255; return o; };
  size_t o_ssum = alloc(2 * NC * 4);
  size_t o_ssq  = alloc(2 * NC * 4);
  size_t o_mean = alloc(2 * NC * 4);
  size_t o_inv  = alloc(2 * NC * 4);
  size_t o_wb   = alloc((size_t)NV * NC * 2);
  size_t o_ca   = alloc((size_t)2 * NBAT * NKC * NC * 4);
  size_t o_smca = alloc((size_t)2 * NBAT * NKC * NP * 4);
  size_t fixed = off;

  const size_t PB  = (size_t)NP * NC * 2;     // 4.72 MB bf16 plane
  const size_t ATT = (size_t)NP * NL * 2;     // 3.54 MB
  const size_t QB  = (size_t)NP * NCQ * 2;    // 0.59 MB
  size_t per_b = 8 * PB + 2 * ATT + 4 * QB;   // 47.2 MB per batch
  int NB = 8;
  while (NB > 1 && fixed + (size_t)NB * per_b + 8192 > ws_size) NB >>= 1;

  size_t o_xnT = alloc((size_t)NB * PB);
  size_t o_xnS = alloc((size_t)NB * PB);
  size_t o_v1T = alloc((size_t)NB * PB);
  size_t o_v1S = alloc((size_t)NB * PB);
  size_t o_v2T = alloc((size_t)NB * PB);
  size_t o_v2S = alloc((size_t)NB * PB);
  size_t o_ohT = alloc((size_t)NB * PB);
  size_t o_ohS = alloc((size_t)NB * PB);
  size_t o_aT  = alloc((size_t)NB * ATT);
  size_t o_aS  = alloc((size_t)NB * ATT);
  size_t o_qT  = alloc((size_t)NB * QB);
  size_t o_kT  = alloc((size_t)NB * QB);
  size_t o_qS  = alloc((size_t)NB * QB);
  size_t o_kS  = alloc((size_t)NB * QB);

  float* ssum = (float*)(base + o_ssum);
  float* ssq  = (float*)(base + o_ssq);
  float* mean = (float*)(base + o_mean);
  float* inv  = (float*)(base + o_inv);
  float* ca   = (float*)(base + o_ca);
  float* smca = (float*)(base + o_smca);
  unsigned short* Wb  = (unsigned short*)(base + o_wb);
  unsigned short* XNT = (unsigned short*)(base + o_xnT);
  unsigned short* XNS = (unsigned short*)(base + o_xnS);
  unsigned short* V1T = (unsigned short*)(base + o_v1T);
  unsigned short* V1S = (unsigned short*)(base + o_v1S);
  unsigned short* V2T = (unsigned short*)(base + o_v2T);
  unsigned short* V2S = (unsigned short*)(base + o_v2S);
  unsigned short* OHT = (unsigned short*)(base + o_ohT);
  unsigned short* OHS = (unsigned short*)(base + o_ohS);
  unsigned short* attT= (unsigned short*)(base + o_aT);
  unsigned short* attS= (unsigned short*)(base + o_aS);
  unsigned short* qT  = (unsigned short*)(base + o_qT);
  unsigned short* kT  = (unsigned short*)(base + o_kT);
  unsigned short* qS  = (unsigned short*)(base + o_qS);
  unsigned short* kS  = (unsigned short*)(base + o_kS);

  hipMemsetAsync(d_out, 0, 4, stream);
  hipMemsetAsync(base + o_ssum, 0, 4096, stream);
  hipMemsetAsync(base + o_ca, 0, (size_t)2 * NBAT * NKC * NC * 4, stream);

  k_stats<<<dim3(2 * NC * NBAT), 256, 0, stream>>>(S, T, ssum, ssq);
  k_finalize<<<1, 512, 0, stream>>>(ssum, ssq, mean, inv);
  k_wconv<<<dim3(NV), 256, 0, stream>>>(wv, wq, wk, Wb);

  for (int b0 = 0; b0 < NBAT; b0 += NB){
    k_xn<<<dim3(144, 4, 2 * NB), 256, 0, stream>>>(S, T, b0, mean, inv, XNT, XNS);
    k_caM<<<dim3(36, NB, 2), 256, 0, stream>>>(XNT, XNS, wcls, b0, smca);
    k_caSoftmax<<<dim3(2 * NB * NKC), 256, 0, stream>>>(smca, b0);
    k_caOut<<<dim3(36, NB, 2), 256, 0, stream>>>(XNT, XNS, smca, b0, ca);
    k_v<<<dim3(144, 2 * NB), 256, 0, stream>>>(XNT, XNS, Wb, bv, bq, bk,
                                               V1T, V1S, qT, kT, qS, kS);
    k_vt<<<dim3(256, 2 * NB), 256, 0, stream>>>(V1T, V1S, V2T, V2S);
    k_e<<<dim3(96, 2 * NB, 2), 256, 0, stream>>>(qT, kT, qS, kS, attT, attS);
    k_attSoftmax<<<dim3(2 * NB * NP / 4), 256, 0, stream>>>(attT, attS, NB * NP);
    k_outH<<<dim3(96, 2 * NB, 4), 256, 0, stream>>>(V2T, V2S, attT, attS, OHT, OHS);
    k_outWL<<<dim3(96, NB, 4), 256, 0, stream>>>(V1T, attT, OHT, V1S, attS, OHS,
                                                 XNT, XNS, gamma, out);
  }
  k_caLoss<<<dim3(48), 256, 0, stream>>>(ca, out);
}

// Round 6
// 611.091 us; speedup vs baseline: 1.4060x; 1.0595x over previous
//
#include <hip/hip_runtime.h>
#include <math.h>

#define NBAT 8
#define NC   256
#define NH   96
#define NW   96
#define NP   9216
#define NCQ  32
#define NKC  6
#define NV   320          // 256 v-channels + 32 q + 32 k
#define NTOT 73728        // NBAT*NP

typedef __attribute__((ext_vector_type(4))) float  floatx4;
typedef __attribute__((ext_vector_type(8))) short  short8;

// ---------- bf16 helpers (storage only; math fp32) ----------
__device__ __forceinline__ float bf2f(unsigned short h){
  return __uint_as_float(((unsigned)h) << 16);
}
__device__ __forceinline__ unsigned short f2bf(float f){
  unsigned u = __float_as_uint(f);
  u += 0x7FFFu + ((u >> 16) & 1u);
  return (unsigned short)(u >> 16);
}

union F4 { float4 v; float a[4]; };

// ---------- reductions ----------
__device__ __forceinline__ float warpReduceSum(float v){
  #pragma unroll
  for (int m = 32; m; m >>= 1) v += __shfl_xor(v, m);
  return v;
}
__device__ __forceinline__ float warpReduceMax(float v){
  #pragma unroll
  for (int m = 32; m; m >>= 1) v = fmaxf(v, __shfl_xor(v, m));
  return v;
}
__device__ float blockReduceSum(float v){
  __shared__ float lds[8];
  v = warpReduceSum(v);
  int wid = threadIdx.x >> 6, lane = threadIdx.x & 63;
  int nw = blockDim.x >> 6;
  if (lane == 0) lds[wid] = v;
  __syncthreads();
  if (wid == 0){
    v = (lane < nw) ? lds[lane] : 0.f;
    #pragma unroll
    for (int m = 4; m; m >>= 1) v += __shfl_xor(v, m);
  }
  __syncthreads();
  return v;  // valid on thread 0
}
__device__ float blockReduceMax(float v){
  __shared__ float lds[8];
  v = warpReduceMax(v);
  int wid = threadIdx.x >> 6, lane = threadIdx.x & 63;
  int nw = blockDim.x >> 6;
  if (lane == 0) lds[wid] = v;
  __syncthreads();
  if (wid == 0){
    v = (lane < nw) ? lds[lane] : -INFINITY;
    #pragma unroll
    for (int m = 4; m; m >>= 1) v = fmaxf(v, __shfl_xor(v, m));
  }
  __syncthreads();
  return v;
}

// ---------- 1. per-channel stats (fully unrolled: 9 loads in flight) ----------
__global__ __launch_bounds__(256)
void k_stats(const float* __restrict__ S, const float* __restrict__ T,
             float* __restrict__ s_sum, float* __restrict__ s_sq){
  int blk = blockIdx.x;                 // 2*C*B = 4096
  int t = blk / (NC * NBAT);
  int rem = blk % (NC * NBAT);
  int c = rem / NBAT;
  int n = rem % NBAT;
  const float4* x4 = (const float4*)((t ? T : S) + ((size_t)n * NC + c) * NP);
  F4 f[9];
  #pragma unroll
  for (int j = 0; j < 9; j++) f[j].v = x4[threadIdx.x + j * 256];
  float s = 0.f, q = 0.f;
  #pragma unroll
  for (int j = 0; j < 9; j++)
    #pragma unroll
    for (int e = 0; e < 4; e++){ s += f[j].a[e]; q += f[j].a[e] * f[j].a[e]; }
  s = blockReduceSum(s);
  q = blockReduceSum(q);
  if (threadIdx.x == 0){
    atomicAdd(&s_sum[t * NC + c], s);
    atomicAdd(&s_sq[t * NC + c], q);
  }
}

__global__ __launch_bounds__(512)
void k_finalize(const float* __restrict__ s_sum, const float* __restrict__ s_sq,
                float* __restrict__ mean, float* __restrict__ inv){
  int i = threadIdx.x;
  if (i < 2 * NC){
    float s = s_sum[i], q = s_sq[i];
    float m = s / (float)NTOT;
    float var = (q - s * m) / (float)(NTOT - 1);
    var = fmaxf(var, 0.f);
    mean[i] = m;
    inv[i] = 1.f / (sqrtf(var) + 1e-6f);
  }
}

// ---------- 2. stage normalized x as bf16 XN[bb][p][c]; ts=0 -> T, ts=1 -> S ----------
__global__ __launch_bounds__(256)
void k_xn(const float* __restrict__ S, const float* __restrict__ T, int b0,
          const float* __restrict__ mean, const float* __restrict__ inv,
          unsigned short* __restrict__ XNT, unsigned short* __restrict__ XNS){
  int pt = blockIdx.x, ct = blockIdx.y;                   // (144, 4, 2*NB)
  int bb = blockIdx.z >> 1, ts = blockIdx.z & 1;
  int t = ts ? 0 : 1;
  const float* x0 = ts ? S : T;
  unsigned short* XN = (ts ? XNS : XNT) + (size_t)bb * NP * NC;
  int bg = b0 + bb;
  int p0 = pt * 64, c0 = ct * 64;
  __shared__ float tile[64 * 65];
  const float* x = x0 + ((size_t)bg * NC + c0) * NP + p0;
  #pragma unroll
  for (int i = 0; i < 4; i++){
    int idx = threadIdx.x + i * 256;       // 64 c-rows x 16 float4 groups
    int r = idx >> 4, g = (idx & 15) * 4;
    F4 f; f.v = *(const float4*)(x + (size_t)r * NP + g);
    float m = mean[t * NC + c0 + r], iv = inv[t * NC + c0 + r];
    #pragma unroll
    for (int j = 0; j < 4; j++) tile[(g + j) * 65 + r] = (f.a[j] - m) * iv;
  }
  __syncthreads();
  #pragma unroll
  for (int i = 0; i < 4; i++){
    int idx = threadIdx.x + i * 256;       // 64 p-rows x 16 groups of 4c
    int p = idx >> 4, g = (idx & 15) * 4;
    unsigned lo = (unsigned)f2bf(tile[p * 65 + g + 0]) | ((unsigned)f2bf(tile[p * 65 + g + 1]) << 16);
    unsigned hi = (unsigned)f2bf(tile[p * 65 + g + 2]) | ((unsigned)f2bf(tile[p * 65 + g + 3]) << 16);
    uint2 u; u.x = lo; u.y = hi;
    *(uint2*)(XN + ((size_t)(p0 + p)) * NC + c0 + g) = u;
  }
}

// ---------- 3. causal attention from XN (bf16) ----------
__global__ __launch_bounds__(256)
void k_caM(const unsigned short* __restrict__ XNT, const unsigned short* __restrict__ XNS,
           const float* __restrict__ wcls, int b0,
           float* __restrict__ smca){
  int pt = blockIdx.x, bb = blockIdx.y, ts = blockIdx.z;   // (36, NB, 2)
  int t = ts ? 0 : 1;
  const unsigned short* XN = (ts ? XNS : XNT) + (size_t)bb * NP * NC;
  __shared__ float wcf[NKC * NC];
  for (int idx = threadIdx.x; idx < NKC * NC; idx += 256) wcf[idx] = wcls[idx];
  __syncthreads();
  int p = pt * 256 + threadIdx.x;
  const unsigned short* row = XN + (size_t)p * NC;
  float acc[NKC];
  #pragma unroll
  for (int k = 0; k < NKC; k++) acc[k] = 0.f;
  for (int c = 0; c < NC; c += 8){
    short8 v = *(const short8*)(row + c);
    #pragma unroll
    for (int j = 0; j < 8; j++){
      float xv = bf2f((unsigned short)v[j]);
      #pragma unroll
      for (int k = 0; k < NKC; k++) acc[k] += wcf[k * NC + c + j] * xv;
    }
  }
  size_t base = ((size_t)(t * NBAT + b0 + bb) * NKC) * NP + p;
  #pragma unroll
  for (int k = 0; k < NKC; k++) smca[base + (size_t)k * NP] = acc[k];
}

__global__ __launch_bounds__(256)
void k_caSoftmax(float* __restrict__ smca, int b0){
  int r = blockIdx.x;                        // 2*NB*NKC rows
  int bb = r / (2 * NKC);
  int rem = r % (2 * NKC);
  int ts = rem / NKC, k = rem % NKC;
  int t = ts ? 0 : 1;
  float* row = smca + ((size_t)(t * NBAT + b0 + bb) * NKC + k) * NP;
  float m = -INFINITY;
  for (int p = threadIdx.x; p < NP; p += 256) m = fmaxf(m, row[p]);
  m = blockReduceMax(m);
  __shared__ float bm, bs;
  if (threadIdx.x == 0) bm = m;
  __syncthreads();
  m = bm;
  float s = 0.f;
  for (int p = threadIdx.x; p < NP; p += 256) s += expf(row[p] - m);
  s = blockReduceSum(s);
  if (threadIdx.x == 0) bs = 1.f / s;
  __syncthreads();
  float rs = bs;
  for (int p = threadIdx.x; p < NP; p += 256) row[p] = expf(row[p] - m) * rs;
}

__global__ __launch_bounds__(256)
void k_caOut(const unsigned short* __restrict__ XNT, const unsigned short* __restrict__ XNS,
             const float* __restrict__ smca, int b0,
             float* __restrict__ ca){
  int ks = blockIdx.x, bb = blockIdx.y, ts = blockIdx.z;   // (36, NB, 2)
  int t = ts ? 0 : 1;
  const unsigned short* XN = (ts ? XNS : XNT) + (size_t)bb * NP * NC;
  int p0 = ks * 256;
  __shared__ float smt[NKC * 256];
  const float* smbase = smca + (size_t)(t * NBAT + b0 + bb) * NKC * NP;
  for (int idx = threadIdx.x; idx < NKC * 256; idx += 256){
    int k = idx >> 8, pp = idx & 255;
    smt[idx] = smbase[(size_t)k * NP + p0 + pp];
  }
  __syncthreads();
  int c = threadIdx.x;
  float acc[NKC];
  #pragma unroll
  for (int k = 0; k < NKC; k++) acc[k] = 0.f;
  const unsigned short* xp = XN + (size_t)p0 * NC + c;
  for (int pp = 0; pp < 256; pp++){
    float xv = bf2f(xp[(size_t)pp * NC]);
    #pragma unroll
    for (int k = 0; k < NKC; k++) acc[k] += smt[k * 256 + pp] * xv;
  }
  float* cab = ca + ((size_t)(t * NBAT + b0 + bb) * NKC) * NC + c;
  #pragma unroll
  for (int k = 0; k < NKC; k++) atomicAdd(&cab[(size_t)k * NC], acc[k]);
}

__global__ __launch_bounds__(256)
void k_caLoss(const float* __restrict__ ca, float* __restrict__ out){
  int i = blockIdx.x * 256 + threadIdx.x;   // 12288 total
  float d = 0.f;
  if (i < NBAT * NKC * NC) d = ca[(size_t)NBAT * NKC * NC + i] - ca[i];
  float ss = blockReduceSum(d * d);
  if (threadIdx.x == 0) atomicAdd(out, ss * (0.0005f / 8.0f));
}

// ---------- 3b. pre-convert W (v|q|k) to bf16 Wb[320][256] ----------
__global__ __launch_bounds__(256)
void k_wconv(const float* __restrict__ wv, const float* __restrict__ wq,
             const float* __restrict__ wk, unsigned short* __restrict__ Wb){
  int n = blockIdx.x;         // 320
  const float* src = (n < 256) ? (wv + (size_t)n * NC)
                   : (n < 288) ? (wq + (size_t)(n - 256) * NC)
                               : (wk + (size_t)(n - 288) * NC);
  Wb[(size_t)n * NC + threadIdx.x] = f2bf(src[threadIdx.x]);
}

// ---------- 4. MFMA GEMM -> V1b[h][c][96w] (c-blocked-contiguous) + q,k [p][cq] ----------
__global__ __launch_bounds__(256)
void k_v(const unsigned short* __restrict__ XNT, const unsigned short* __restrict__ XNS,
         const unsigned short* __restrict__ Wb,
         const float* __restrict__ bv, const float* __restrict__ bq,
         const float* __restrict__ bk,
         unsigned short* __restrict__ V1T, unsigned short* __restrict__ V1S,
         unsigned short* __restrict__ qT, unsigned short* __restrict__ kT,
         unsigned short* __restrict__ qS, unsigned short* __restrict__ kS){
  int pt = blockIdx.x;                       // (144, 2*NB)
  int bb = blockIdx.y >> 1, ts = blockIdx.y & 1;
  const unsigned short* XN = (ts ? XNS : XNT) + (size_t)bb * NP * NC;
  unsigned short* V1 = (ts ? V1S : V1T) + (size_t)bb * NP * NC;
  unsigned short* qb  = (ts ? qS : qT) + (size_t)bb * NP * NCQ;
  unsigned short* kb  = (ts ? kS : kT) + (size_t)bb * NP * NCQ;
  int p0 = pt * 64;
  __shared__ unsigned short Wl[NV * 40];
  int lane = threadIdx.x & 63;
  int wid = threadIdx.x >> 6;
  int col = lane & 15, quad = lane >> 4;
  const unsigned short* xnb = XN + (size_t)(p0 + wid * 16 + col) * NC;
  floatx4 acc[20];
  #pragma unroll
  for (int nt = 0; nt < 20; nt++) acc[nt] = (floatx4){0.f, 0.f, 0.f, 0.f};

  int ci_n[5], ci_k8[5];
  #pragma unroll
  for (int i = 0; i < 5; i++){ int ci = i * 256 + threadIdx.x; ci_n[i] = ci >> 2; ci_k8[i] = (ci & 3) * 8; }

  short8 w[5];
  #pragma unroll
  for (int i = 0; i < 5; i++)
    w[i] = *(const short8*)(Wb + (size_t)ci_n[i] * NC + ci_k8[i]);

  for (int ks = 0; ks < 8; ks++){
    if (ks) __syncthreads();
    #pragma unroll
    for (int i = 0; i < 5; i++)
      *(short8*)(Wl + ci_n[i] * 40 + ci_k8[i]) = w[i];
    __syncthreads();
    if (ks < 7){
      int k0n = (ks + 1) * 32;
      #pragma unroll
      for (int i = 0; i < 5; i++)
        w[i] = *(const short8*)(Wb + (size_t)ci_n[i] * NC + k0n + ci_k8[i]);
    }
    short8 a = *(const short8*)(xnb + ks * 32 + quad * 8);
    #pragma unroll
    for (int nt = 0; nt < 20; nt++){
      short8 b = *(const short8*)(Wl + (nt * 16 + col) * 40 + quad * 8);
      acc[nt] = __builtin_amdgcn_mfma_f32_16x16x32_bf16(a, b, acc[nt], 0, 0, 0);
    }
  }

  int prow0 = p0 + wid * 16 + quad * 4;
  int hh = prow0 / 96, ww = prow0 % 96;     // 4-row group never crosses h (4 | 96)
  #pragma unroll
  for (int nt = 0; nt < 16; nt++){
    int c = nt * 16 + col;
    float bias = bv[c];
    uint2 u;
    u.x = (unsigned)f2bf(acc[nt][0] + bias) | ((unsigned)f2bf(acc[nt][1] + bias) << 16);
    u.y = (unsigned)f2bf(acc[nt][2] + bias) | ((unsigned)f2bf(acc[nt][3] + bias) << 16);
    *(uint2*)(V1 + ((size_t)(hh * 256 + c)) * 96 + ww) = u;
  }
  #pragma unroll
  for (int nt = 16; nt < 18; nt++){
    int c = (nt - 16) * 16 + col;
    float bias = bq[c];
    #pragma unroll
    for (int i = 0; i < 4; i++)
      qb[((size_t)(prow0 + i)) * NCQ + c] = f2bf(acc[nt][i] + bias);
  }
  #pragma unroll
  for (int nt = 18; nt < 20; nt++){
    int c = (nt - 18) * 16 + col;
    float bias = bk[c];
    #pragma unroll
    for (int i = 0; i < 4; i++)
      kb[((size_t)(prow0 + i)) * NCQ + c] = f2bf(acc[nt][i] + bias);
  }
}

// ---------- 4b. transpose V1b[h][c][w] -> V2b[w][c][h], 2 channels per block ----------
__global__ __launch_bounds__(256)
void k_vt(const unsigned short* __restrict__ V1T, const unsigned short* __restrict__ V1S,
          unsigned short* __restrict__ V2T, unsigned short* __restrict__ V2S){
  int cp = blockIdx.x;                       // (128, 2*NB)
  int bb = blockIdx.y >> 1, ts = blockIdx.y & 1;
  const unsigned short* V1 = (ts ? V1S : V1T) + (size_t)bb * NP * NC;
  unsigned short* V2 = (ts ? V2S : V2T) + (size_t)bb * NP * NC;
  int c0 = cp * 2;
  __shared__ unsigned short tile[2 * 96 * 104];   // [cl][w][h], 39.9 KB
  #pragma unroll
  for (int k = 0; k < 9; k++){
    int idx = threadIdx.x + k * 256;              // 2304 short8 chunks
    int cl = idx / 1152, rem = idx % 1152;
    int h = rem / 12, g = rem % 12;
    short8 v = *(const short8*)(V1 + ((size_t)(h * 256 + c0 + cl)) * 96 + g * 8);
    #pragma unroll
    for (int jj = 0; jj < 8; jj++)
      tile[cl * 9984 + (g * 8 + jj) * 104 + h] = ((unsigned short*)&v)[jj];
  }
  __syncthreads();
  #pragma unroll
  for (int k = 0; k < 9; k++){
    int idx = threadIdx.x + k * 256;
    int cl = idx / 1152, rem = idx % 1152;
    int w = rem / 12, g = rem % 12;
    short8 v = *(const short8*)(tile + cl * 9984 + w * 104 + g * 8);
    *(short8*)(V2 + ((size_t)(w * 256 + c0 + cl)) * 96 + g * 8) = v;
  }
}

// ---------- 5+6. scores -> attHt[w*96+i][96] (which=0, diag mask) / attW[p][96] (which=1)
__global__ __launch_bounds__(256)
void k_e(const unsigned short* __restrict__ qT, const unsigned short* __restrict__ kT,
         const unsigned short* __restrict__ qS, const unsigned short* __restrict__ kS,
         unsigned short* __restrict__ attHtT, unsigned short* __restrict__ attWT,
         unsigned short* __restrict__ attHtS, unsigned short* __restrict__ attWS){
  int x = blockIdx.x, which = blockIdx.z;    // (96, 2*NB, 2)
  int bb = blockIdx.y >> 1, ts = blockIdx.y & 1;
  const unsigned short* qb = (ts ? qS : qT) + (size_t)bb * NP * NCQ;
  const unsigned short* kb = (ts ? kS : kT) + (size_t)bb * NP * NCQ;
  unsigned short* att = (which ? (ts ? attWS : attWT) : (ts ? attHtS : attHtT))
                        + (size_t)bb * NP * 96;
  int lane = threadIdx.x & 63, wid = threadIdx.x >> 6;
  int col = lane & 15, quad = lane >> 4;
  int mi0 = (wid & 1) * 3, ni0 = (wid >> 1) * 3;
  short8 a[3], b[3];
  if (which == 0){            // eH: fixed w=x, queries (i,x)
    #pragma unroll
    for (int m = 0; m < 3; m++)
      a[m] = *(const short8*)(qb + ((size_t)(((mi0 + m) * 16 + col) * 96 + x)) * NCQ + quad * 8);
    #pragma unroll
    for (int n = 0; n < 3; n++)
      b[n] = *(const short8*)(kb + ((size_t)(((ni0 + n) * 16 + col) * 96 + x)) * NCQ + quad * 8);
  } else {                    // eW: fixed h=x, queries (x,i)
    #pragma unroll
    for (int m = 0; m < 3; m++)
      a[m] = *(const short8*)(qb + ((size_t)(x * 96 + (mi0 + m) * 16 + col)) * NCQ + quad * 8);
    #pragma unroll
    for (int n = 0; n < 3; n++)
      b[n] = *(const short8*)(kb + ((size_t)(x * 96 + (ni0 + n) * 16 + col)) * NCQ + quad * 8);
  }
  floatx4 acc[3][3];
  #pragma unroll
  for (int m = 0; m < 3; m++)
    #pragma unroll
    for (int n = 0; n < 3; n++){
      acc[m][n] = (floatx4){0.f, 0.f, 0.f, 0.f};
      acc[m][n] = __builtin_amdgcn_mfma_f32_16x16x32_bf16(a[m], b[n], acc[m][n], 0, 0, 0);
    }
  #pragma unroll
  for (int m = 0; m < 3; m++)
    #pragma unroll
    for (int n = 0; n < 3; n++){
      int j = (ni0 + n) * 16 + col;
      #pragma unroll
      for (int r = 0; r < 4; r++){
        int i = (mi0 + m) * 16 + quad * 4 + r;
        float v = (!which && j == i) ? -INFINITY : acc[m][n][r];
        att[((size_t)(x * 96 + i)) * 96 + j] = f2bf(v);   // contiguous slab per block
      }
    }
}

// ---------- 7. softmax over 192 per query (across attHt + attW planes) ----------
__global__ __launch_bounds__(256)
void k_attSoftmax(unsigned short* __restrict__ attHtT, unsigned short* __restrict__ attWT,
                  unsigned short* __restrict__ attHtS, unsigned short* __restrict__ attWS,
                  int nbp){                   // nbp = NB*NP
  int q = blockIdx.x * 4 + (threadIdx.x >> 6);
  int lane = threadIdx.x & 63;
  int sS = (q >= nbp);
  int ql = sS ? q - nbp : q;
  unsigned short* aHt = sS ? attHtS : attHtT;
  unsigned short* aW  = sS ? attWS  : attWT;
  int bb = ql / NP, p = ql % NP;
  unsigned short* rowW = aW  + ((size_t)(bb * NP + p)) * 96;
  unsigned short* rowH = aHt + ((size_t)(bb * NP + (p % 96) * 96 + p / 96)) * 96;
  float h0 = bf2f(rowH[lane]);
  float w0 = bf2f(rowW[lane]);
  float h1 = (lane < 32) ? bf2f(rowH[64 + lane]) : -INFINITY;
  float w1 = (lane < 32) ? bf2f(rowW[64 + lane]) : -INFINITY;
  float m = fmaxf(fmaxf(h0, h1), fmaxf(w0, w1));
  m = warpReduceMax(m);
  float xh0 = expf(h0 - m), xw0 = expf(w0 - m);
  float xh1 = (lane < 32) ? expf(h1 - m) : 0.f;
  float xw1 = (lane < 32) ? expf(w1 - m) : 0.f;
  float s = warpReduceSum(xh0 + xw0 + xh1 + xw1);
  float rs = 1.f / s;
  rowH[lane] = f2bf(xh0 * rs);
  rowW[lane] = f2bf(xw0 * rs);
  if (lane < 32){
    rowH[64 + lane] = f2bf(xh1 * rs);
    rowW[64 + lane] = f2bf(xw1 * rs);
  }
}

// ---------- 8. outH: OHb[cs][i*96+w][64c] = attHt[w-slab] x V2b[w][c][h] ----------
__global__ __launch_bounds__(256)
void k_outH(const unsigned short* __restrict__ V2T, const unsigned short* __restrict__ V2S,
            const unsigned short* __restrict__ attHtT, const unsigned short* __restrict__ attHtS,
            unsigned short* __restrict__ OHT, unsigned short* __restrict__ OHS){
  int w = blockIdx.x, cs = blockIdx.z;       // (96, 2*NB, 4)
  int bb = blockIdx.y >> 1, ts = blockIdx.y & 1;
  const unsigned short* V2 = (ts ? V2S : V2T) + (size_t)bb * NP * NC;
  const unsigned short* att = (ts ? attHtS : attHtT) + (size_t)bb * NP * 96;
  unsigned short* OH = (ts ? OHS : OHT) + (size_t)bb * NP * NC + (size_t)cs * NP * 64;
  int lane = threadIdx.x & 63, wid = threadIdx.x >> 6;
  int col = lane & 15, quad = lane >> 4;
  int cl = wid * 16 + col;
  int c = cs * 64 + cl;
  floatx4 acc[6];
  #pragma unroll
  for (int m = 0; m < 6; m++) acc[m] = (floatx4){0.f, 0.f, 0.f, 0.f};
  #pragma unroll
  for (int ks = 0; ks < 3; ks++){
    int k0 = ks * 32 + quad * 8;
    short8 a[6], b;
    #pragma unroll
    for (int m = 0; m < 6; m++)
      a[m] = *(const short8*)(att + ((size_t)(w * 96 + m * 16 + col)) * 96 + k0);
    b = *(const short8*)(V2 + ((size_t)(w * 256 + c)) * 96 + k0);
    #pragma unroll
    for (int m = 0; m < 6; m++)
      acc[m] = __builtin_amdgcn_mfma_f32_16x16x32_bf16(a[m], b, acc[m], 0, 0, 0);
  }
  #pragma unroll
  for (int m = 0; m < 6; m++){
    #pragma unroll
    for (int r = 0; r < 4; r++){
      int i = m * 16 + quad * 4 + r;
      OH[((size_t)(i * 96 + w)) * 64 + cl] = f2bf(acc[m][r]);
    }
  }
}

// ---------- 9. combined outW(T,S) + fused loss; all slabs contiguous ----------
__global__ __launch_bounds__(256)
void k_outWL(const unsigned short* __restrict__ V1T, const unsigned short* __restrict__ attWT,
             const unsigned short* __restrict__ OHT,
             const unsigned short* __restrict__ V1S, const unsigned short* __restrict__ attWS,
             const unsigned short* __restrict__ OHS,
             const unsigned short* __restrict__ XNT, const unsigned short* __restrict__ XNS,
             const float* __restrict__ gamma,
             float* __restrict__ out){
  int h = blockIdx.x, bb = blockIdx.y, cs = blockIdx.z;    // (96, NB, 4)
  size_t pb = (size_t)bb * NP * NC;
  int lane = threadIdx.x & 63, wid = threadIdx.x >> 6;
  int col = lane & 15, quad = lane >> 4;
  int cl = wid * 16 + col;
  int c  = cs * 64 + cl;

  __shared__ unsigned short ohTl[96 * 72];   // [i][cl], stride 72
  __shared__ unsigned short ohSl[96 * 72];
  __shared__ unsigned short dnl [96 * 72];

  const unsigned short* OHTb = OHT + pb + (size_t)cs * NP * 64 + (size_t)(h * 96) * 64;
  const unsigned short* OHSb = OHS + pb + (size_t)cs * NP * 64 + (size_t)(h * 96) * 64;
  #pragma unroll
  for (int k = 0; k < 3; k++){
    int g = threadIdx.x + k * 256;           // 768 x 16B, OH slabs fully linear
    int i = g >> 3, cc = (g & 7) * 8;
    short8 ot = *(const short8*)(OHTb + g * 8);
    short8 os = *(const short8*)(OHSb + g * 8);
    size_t gx = pb + ((size_t)(h * 96 + i)) * NC + cs * 64 + cc;
    short8 xt = *(const short8*)(XNT + gx);
    short8 xs = *(const short8*)(XNS + gx);
    short8 dn;
    #pragma unroll
    for (int j = 0; j < 8; j++)
      ((unsigned short*)&dn)[j] = f2bf(bf2f((unsigned short)xt[j]) - bf2f((unsigned short)xs[j]));
    *(short8*)(ohTl + i * 72 + cc) = ot;
    *(short8*)(ohSl + i * 72 + cc) = os;
    *(short8*)(dnl  + i * 72 + cc) = dn;
  }
  __syncthreads();

  floatx4 accT[6], accS[6];
  #pragma unroll
  for (int m = 0; m < 6; m++){
    accT[m] = (floatx4){0.f, 0.f, 0.f, 0.f};
    accS[m] = (floatx4){0.f, 0.f, 0.f, 0.f};
  }
  #pragma unroll
  for (int ks = 0; ks < 3; ks++){
    int k0 = ks * 32 + quad * 8;
    short8 a[6], b;
    #pragma unroll
    for (int m = 0; m < 6; m++)
      a[m] = *(const short8*)(attWT + (size_t)bb * NP * 96 + ((size_t)(h * 96 + m * 16 + col)) * 96 + k0);
    b = *(const short8*)(V1T + pb + ((size_t)(h * 256 + c)) * 96 + k0);
    #pragma unroll
    for (int m = 0; m < 6; m++)
      accT[m] = __builtin_amdgcn_mfma_f32_16x16x32_bf16(a[m], b, accT[m], 0, 0, 0);
  }
  #pragma unroll
  for (int ks = 0; ks < 3; ks++){
    int k0 = ks * 32 + quad * 8;
    short8 a[6], b;
    #pragma unroll
    for (int m = 0; m < 6; m++)
      a[m] = *(const short8*)(attWS + (size_t)bb * NP * 96 + ((size_t)(h * 96 + m * 16 + col)) * 96 + k0);
    b = *(const short8*)(V1S + pb + ((size_t)(h * 256 + c)) * 96 + k0);
    #pragma unroll
    for (int m = 0; m < 6; m++)
      accS[m] = __builtin_amdgcn_mfma_f32_16x16x32_bf16(a[m], b, accS[m], 0, 0, 0);
  }

  float g = gamma[0];
  float ss = 0.f;
  #pragma unroll
  for (int m = 0; m < 6; m++){
    int i0 = m * 16 + quad * 4;
    #pragma unroll
    for (int r = 0; r < 4; r++){
      int i = i0 + r;
      float oT = accT[m][r] + bf2f(ohTl[i * 72 + cl]);
      float oS = accS[m][r] + bf2f(ohSl[i * 72 + cl]);
      float d = g * (oT - oS) + bf2f(dnl[i * 72 + cl]);
      ss += d * d;
    }
  }
  ss = blockReduceSum(ss);
  if (threadIdx.x == 0) atomicAdd(out, ss * (1e-5f / 8.0f));
}

// ---------- host ----------
extern "C" void kernel_launch(void* const* d_in, const int* in_sizes, int n_in,
                              void* d_out, int out_size, void* d_ws, size_t ws_size,
                              hipStream_t stream){
  (void)in_sizes; (void)n_in; (void)out_size;
  const float* S    = (const float*)d_in[0];
  const float* T    = (const float*)d_in[1];
  const float* wcls = (const float*)d_in[2];
  const float* wq   = (const float*)d_in[3];
  const float* bq   = (const float*)d_in[4];
  const float* wk   = (const float*)d_in[5];
  const float* bk   = (const float*)d_in[6];
  const float* wv   = (const float*)d_in[7];
  const float* bv   = (const float*)d_in[8];
  const float* gamma= (const float*)d_in[9];
  float* out = (float*)d_out;

  char* base = (char*)d_ws;
  size_t off = 0;
  auto alloc = [&](size_t b){ size_t o = off; off += (b + 255) & ~(size_t)255; return o; };
  size_t o_ssum = alloc(2 * NC * 4);
  size_t o_ssq  = alloc(2 * NC * 4);
  size_t o_mean = alloc(2 * NC * 4);
  size_t o_inv  = alloc(2 * NC * 4);
  size_t o_wb   = alloc((size_t)NV * NC * 2);
  size_t o_ca   = alloc((size_t)2 * NBAT * NKC * NC * 4);
  size_t o_smca = alloc((size_t)2 * NBAT * NKC * NP * 4);
  size_t fixed = off;

  const size_t PB  = (size_t)NP * NC * 2;     // 4.72 MB bf16 plane
  const size_t AT1 = (size_t)NP * 96 * 2;     // 1.77 MB att half-plane
  const size_t QB  = (size_t)NP * NCQ * 2;    // 0.59 MB
  size_t per_b = 8 * PB + 4 * AT1 + 4 * QB;   // 47.2 MB per batch
  int NB = 8;
  while (NB > 1 && fixed + (size_t)NB * per_b + 8192 > ws_size) NB >>= 1;

  size_t o_xnT = alloc((size_t)NB * PB);
  size_t o_xnS = alloc((size_t)NB * PB);
  size_t o_v1T = alloc((size_t)NB * PB);
  size_t o_v1S = alloc((size_t)NB * PB);
  size_t o_v2T = alloc((size_t)NB * PB);
  size_t o_v2S = alloc((size_t)NB * PB);
  size_t o_ohT = alloc((size_t)NB * PB);
  size_t o_ohS = alloc((size_t)NB * PB);
  size_t o_hT  = alloc((size_t)NB * AT1);
  size_t o_wT  = alloc((size_t)NB * AT1);
  size_t o_hS  = alloc((size_t)NB * AT1);
  size_t o_wS  = alloc((size_t)NB * AT1);
  size_t o_qT  = alloc((size_t)NB * QB);
  size_t o_kT  = alloc((size_t)NB * QB);
  size_t o_qS  = alloc((size_t)NB * QB);
  size_t o_kS  = alloc((size_t)NB * QB);

  float* ssum = (float*)(base + o_ssum);
  float* ssq  = (float*)(base + o_ssq);
  float* mean = (float*)(base + o_mean);
  float* inv  = (float*)(base + o_inv);
  float* ca   = (float*)(base + o_ca);
  float* smca = (float*)(base + o_smca);
  unsigned short* Wb   = (unsigned short*)(base + o_wb);
  unsigned short* XNT  = (unsigned short*)(base + o_xnT);
  unsigned short* XNS  = (unsigned short*)(base + o_xnS);
  unsigned short* V1T  = (unsigned short*)(base + o_v1T);
  unsigned short* V1S  = (unsigned short*)(base + o_v1S);
  unsigned short* V2T  = (unsigned short*)(base + o_v2T);
  unsigned short* V2S  = (unsigned short*)(base + o_v2S);
  unsigned short* OHT  = (unsigned short*)(base + o_ohT);
  unsigned short* OHS  = (unsigned short*)(base + o_ohS);
  unsigned short* aHtT = (unsigned short*)(base + o_hT);
  unsigned short* aWT  = (unsigned short*)(base + o_wT);
  unsigned short* aHtS = (unsigned short*)(base + o_hS);
  unsigned short* aWS  = (unsigned short*)(base + o_wS);
  unsigned short* qT   = (unsigned short*)(base + o_qT);
  unsigned short* kT   = (unsigned short*)(base + o_kT);
  unsigned short* qS   = (unsigned short*)(base + o_qS);
  unsigned short* kS   = (unsigned short*)(base + o_kS);

  hipMemsetAsync(d_out, 0, 4, stream);
  hipMemsetAsync(base + o_ssum, 0, 4096, stream);
  hipMemsetAsync(base + o_ca, 0, (size_t)2 * NBAT * NKC * NC * 4, stream);

  k_stats<<<dim3(2 * NC * NBAT), 256, 0, stream>>>(S, T, ssum, ssq);
  k_finalize<<<1, 512, 0, stream>>>(ssum, ssq, mean, inv);
  k_wconv<<<dim3(NV), 256, 0, stream>>>(wv, wq, wk, Wb);

  for (int b0 = 0; b0 < NBAT; b0 += NB){
    k_xn<<<dim3(144, 4, 2 * NB), 256, 0, stream>>>(S, T, b0, mean, inv, XNT, XNS);
    k_caM<<<dim3(36, NB, 2), 256, 0, stream>>>(XNT, XNS, wcls, b0, smca);
    k_caSoftmax<<<dim3(2 * NB * NKC), 256, 0, stream>>>(smca, b0);
    k_caOut<<<dim3(36, NB, 2), 256, 0, stream>>>(XNT, XNS, smca, b0, ca);
    k_v<<<dim3(144, 2 * NB), 256, 0, stream>>>(XNT, XNS, Wb, bv, bq, bk,
                                               V1T, V1S, qT, kT, qS, kS);
    k_vt<<<dim3(128, 2 * NB), 256, 0, stream>>>(V1T, V1S, V2T, V2S);
    k_e<<<dim3(96, 2 * NB, 2), 256, 0, stream>>>(qT, kT, qS, kS, aHtT, aWT, aHtS, aWS);
    k_attSoftmax<<<dim3(2 * NB * NP / 4), 256, 0, stream>>>(aHtT, aWT, aHtS, aWS, NB * NP);
    k_outH<<<dim3(96, 2 * NB, 4), 256, 0, stream>>>(V2T, V2S, aHtT, aHtS, OHT, OHS);
    k_outWL<<<dim3(96, NB, 4), 256, 0, stream>>>(V1T, aWT, OHT, V1S, aWS, OHS,
                                                 XNT, XNS, gamma, out);
  }
  k_caLoss<<<dim3(48), 256, 0, stream>>>(ca, out);
}

// Round 7
// 593.557 us; speedup vs baseline: 1.4475x; 1.0295x over previous
//
#include <hip/hip_runtime.h>
#include <math.h>

#define NBAT 8
#define NC   256
#define NH   96
#define NW   96
#define NP   9216
#define NCQ  32
#define NKC  6
#define NV   320          // 256 v-channels + 32 q + 32 k
#define NTOT 73728        // NBAT*NP

typedef __attribute__((ext_vector_type(4))) float  floatx4;
typedef __attribute__((ext_vector_type(8))) short  short8;

// ---------- bf16 helpers (storage only; math fp32) ----------
__device__ __forceinline__ float bf2f(unsigned short h){
  return __uint_as_float(((unsigned)h) << 16);
}
__device__ __forceinline__ unsigned short f2bf(float f){
  unsigned u = __float_as_uint(f);
  u += 0x7FFFu + ((u >> 16) & 1u);
  return (unsigned short)(u >> 16);
}

union F4 { float4 v; float a[4]; };

// ---------- reductions ----------
__device__ __forceinline__ float warpReduceSum(float v){
  #pragma unroll
  for (int m = 32; m; m >>= 1) v += __shfl_xor(v, m);
  return v;
}
__device__ __forceinline__ float warpReduceMax(float v){
  #pragma unroll
  for (int m = 32; m; m >>= 1) v = fmaxf(v, __shfl_xor(v, m));
  return v;
}
__device__ float blockReduceSum(float v){
  __shared__ float lds[8];
  v = warpReduceSum(v);
  int wid = threadIdx.x >> 6, lane = threadIdx.x & 63;
  int nw = blockDim.x >> 6;
  if (lane == 0) lds[wid] = v;
  __syncthreads();
  if (wid == 0){
    v = (lane < nw) ? lds[lane] : 0.f;
    #pragma unroll
    for (int m = 4; m; m >>= 1) v += __shfl_xor(v, m);
  }
  __syncthreads();
  return v;  // valid on thread 0
}
__device__ float blockReduceMax(float v){
  __shared__ float lds[8];
  v = warpReduceMax(v);
  int wid = threadIdx.x >> 6, lane = threadIdx.x & 63;
  int nw = blockDim.x >> 6;
  if (lane == 0) lds[wid] = v;
  __syncthreads();
  if (wid == 0){
    v = (lane < nw) ? lds[lane] : -INFINITY;
    #pragma unroll
    for (int m = 4; m; m >>= 1) v = fmaxf(v, __shfl_xor(v, m));
  }
  __syncthreads();
  return v;
}

// ---------- 1. per-channel stats (c-fastest block order: contiguous across blocks) ----------
__global__ __launch_bounds__(256)
void k_stats(const float* __restrict__ S, const float* __restrict__ T,
             float* __restrict__ s_sum, float* __restrict__ s_sq){
  int blk = blockIdx.x;                 // 2*B*C = 4096, c fastest
  int t = blk >> 11;
  int n = (blk >> 8) & 7;
  int c = blk & 255;
  const float4* x4 = (const float4*)((t ? T : S) + ((size_t)n * NC + c) * NP);
  F4 f[9];
  #pragma unroll
  for (int j = 0; j < 9; j++) f[j].v = x4[threadIdx.x + j * 256];
  float s = 0.f, q = 0.f;
  #pragma unroll
  for (int j = 0; j < 9; j++)
    #pragma unroll
    for (int e = 0; e < 4; e++){ s += f[j].a[e]; q += f[j].a[e] * f[j].a[e]; }
  s = blockReduceSum(s);
  q = blockReduceSum(q);
  if (threadIdx.x == 0){
    atomicAdd(&s_sum[t * NC + c], s);
    atomicAdd(&s_sq[t * NC + c], q);
  }
}

__global__ __launch_bounds__(512)
void k_finalize(const float* __restrict__ s_sum, const float* __restrict__ s_sq,
                float* __restrict__ mean, float* __restrict__ inv){
  int i = threadIdx.x;
  if (i < 2 * NC){
    float s = s_sum[i], q = s_sq[i];
    float m = s / (float)NTOT;
    float var = (q - s * m) / (float)(NTOT - 1);
    var = fmaxf(var, 0.f);
    mean[i] = m;
    inv[i] = 1.f / (sqrtf(var) + 1e-6f);
  }
}

// ---------- 2. fused: stage XNT/XNS/DN (bf16) + caM partial sums (atomics) ----------
// Both tensors per block; caM computed from pre-rounding fp32 tiles (closer to ref).
__global__ __launch_bounds__(256)
void k_xn(const float* __restrict__ S, const float* __restrict__ T, int b0,
          const float* __restrict__ mean, const float* __restrict__ inv,
          const float* __restrict__ wcls,
          unsigned short* __restrict__ XNT, unsigned short* __restrict__ XNS,
          unsigned short* __restrict__ DN,
          float* __restrict__ smca){
  int pt = blockIdx.x, ct = blockIdx.y, bb = blockIdx.z;  // (144, 4, NB)
  int bg = b0 + bb;
  int p0 = pt * 64, c0 = ct * 64;
  __shared__ float tT[64 * 65];
  __shared__ float tS[64 * 65];
  __shared__ float wl[NKC * 64];
  for (int idx = threadIdx.x; idx < NKC * 64; idx += 256)
    wl[idx] = wcls[(idx >> 6) * NC + c0 + (idx & 63)];
  const float* xT = T + ((size_t)bg * NC + c0) * NP + p0;
  const float* xS = S + ((size_t)bg * NC + c0) * NP + p0;
  #pragma unroll
  for (int i = 0; i < 4; i++){
    int idx = threadIdx.x + i * 256;       // 64 c-rows x 16 float4 p-groups
    int r = idx >> 4, g = (idx & 15) * 4;
    F4 fT, fS;
    fT.v = *(const float4*)(xT + (size_t)r * NP + g);
    fS.v = *(const float4*)(xS + (size_t)r * NP + g);
    float mT = mean[NC + c0 + r], ivT = inv[NC + c0 + r];  // T stats at t=1
    float mS = mean[c0 + r],      ivS = inv[c0 + r];       // S stats at t=0
    #pragma unroll
    for (int j = 0; j < 4; j++){
      tT[(g + j) * 65 + r] = (fT.a[j] - mT) * ivT;
      tS[(g + j) * 65 + r] = (fS.a[j] - mS) * ivS;
    }
  }
  __syncthreads();
  // write XNT / XNS / DN (bf16, [p][c])
  size_t ob = (size_t)bb * NP * NC;
  #pragma unroll
  for (int i = 0; i < 4; i++){
    int idx = threadIdx.x + i * 256;       // 64 p-rows x 16 groups of 4c
    int p = idx >> 4, g = (idx & 15) * 4;
    float vT0 = tT[p * 65 + g + 0], vT1 = tT[p * 65 + g + 1];
    float vT2 = tT[p * 65 + g + 2], vT3 = tT[p * 65 + g + 3];
    float vS0 = tS[p * 65 + g + 0], vS1 = tS[p * 65 + g + 1];
    float vS2 = tS[p * 65 + g + 2], vS3 = tS[p * 65 + g + 3];
    size_t oa = ob + ((size_t)(p0 + p)) * NC + c0 + g;
    uint2 u;
    u.x = (unsigned)f2bf(vT0) | ((unsigned)f2bf(vT1) << 16);
    u.y = (unsigned)f2bf(vT2) | ((unsigned)f2bf(vT3) << 16);
    *(uint2*)(XNT + oa) = u;
    u.x = (unsigned)f2bf(vS0) | ((unsigned)f2bf(vS1) << 16);
    u.y = (unsigned)f2bf(vS2) | ((unsigned)f2bf(vS3) << 16);
    *(uint2*)(XNS + oa) = u;
    u.x = (unsigned)f2bf(vT0 - vS0) | ((unsigned)f2bf(vT1 - vS1) << 16);
    u.y = (unsigned)f2bf(vT2 - vS2) | ((unsigned)f2bf(vT3 - vS3) << 16);
    *(uint2*)(DN + oa) = u;
  }
  // caM partials: M[k][p] += sum_{c in this ct} wcls[k][c] * xn[p][c]
  int p = threadIdx.x >> 2, sub = threadIdx.x & 3;
  float aT[NKC], aS[NKC];
  #pragma unroll
  for (int k = 0; k < NKC; k++){ aT[k] = 0.f; aS[k] = 0.f; }
  #pragma unroll
  for (int c16 = 0; c16 < 16; c16++){
    int cc = sub * 16 + c16;
    float xvT = tT[p * 65 + cc], xvS = tS[p * 65 + cc];
    #pragma unroll
    for (int k = 0; k < NKC; k++){
      aT[k] += wl[k * 64 + cc] * xvT;
      aS[k] += wl[k * 64 + cc] * xvS;
    }
  }
  #pragma unroll
  for (int k = 0; k < NKC; k++){
    aT[k] += __shfl_xor(aT[k], 1); aT[k] += __shfl_xor(aT[k], 2);
    aS[k] += __shfl_xor(aS[k], 1); aS[k] += __shfl_xor(aS[k], 2);
  }
  if (sub == 0){
    float* mTp = smca + ((size_t)(NBAT + bg) * NKC) * NP + (p0 + p);
    float* mSp = smca + ((size_t)bg * NKC) * NP + (p0 + p);
    #pragma unroll
    for (int k = 0; k < NKC; k++){
      atomicAdd(&mTp[(size_t)k * NP], aT[k]);
      atomicAdd(&mSp[(size_t)k * NP], aS[k]);
    }
  }
}

// ---------- 3. ca softmax / out / loss ----------
__global__ __launch_bounds__(256)
void k_caSoftmax(float* __restrict__ smca, int b0){
  int r = blockIdx.x;                        // 2*NB*NKC rows
  int bb = r / (2 * NKC);
  int rem = r % (2 * NKC);
  int ts = rem / NKC, k = rem % NKC;
  int t = ts ? 0 : 1;
  float* row = smca + ((size_t)(t * NBAT + b0 + bb) * NKC + k) * NP;
  float m = -INFINITY;
  for (int p = threadIdx.x; p < NP; p += 256) m = fmaxf(m, row[p]);
  m = blockReduceMax(m);
  __shared__ float bm, bs;
  if (threadIdx.x == 0) bm = m;
  __syncthreads();
  m = bm;
  float s = 0.f;
  for (int p = threadIdx.x; p < NP; p += 256) s += expf(row[p] - m);
  s = blockReduceSum(s);
  if (threadIdx.x == 0) bs = 1.f / s;
  __syncthreads();
  float rs = bs;
  for (int p = threadIdx.x; p < NP; p += 256) row[p] = expf(row[p] - m) * rs;
}

__global__ __launch_bounds__(256)
void k_caOut(const unsigned short* __restrict__ XNT, const unsigned short* __restrict__ XNS,
             const float* __restrict__ smca, int b0,
             float* __restrict__ ca){
  int ks = blockIdx.x, bb = blockIdx.y, ts = blockIdx.z;   // (36, NB, 2)
  int t = ts ? 0 : 1;
  const unsigned short* XN = (ts ? XNS : XNT) + (size_t)bb * NP * NC;
  int p0 = ks * 256;
  __shared__ float smt[NKC * 256];
  const float* smbase = smca + (size_t)(t * NBAT + b0 + bb) * NKC * NP;
  for (int idx = threadIdx.x; idx < NKC * 256; idx += 256){
    int k = idx >> 8, pp = idx & 255;
    smt[idx] = smbase[(size_t)k * NP + p0 + pp];
  }
  __syncthreads();
  int c = threadIdx.x;
  float acc[NKC];
  #pragma unroll
  for (int k = 0; k < NKC; k++) acc[k] = 0.f;
  const unsigned short* xp = XN + (size_t)p0 * NC + c;
  for (int pp = 0; pp < 256; pp++){
    float xv = bf2f(xp[(size_t)pp * NC]);
    #pragma unroll
    for (int k = 0; k < NKC; k++) acc[k] += smt[k * 256 + pp] * xv;
  }
  float* cab = ca + ((size_t)(t * NBAT + b0 + bb) * NKC) * NC + c;
  #pragma unroll
  for (int k = 0; k < NKC; k++) atomicAdd(&cab[(size_t)k * NC], acc[k]);
}

__global__ __launch_bounds__(256)
void k_caLoss(const float* __restrict__ ca, float* __restrict__ out){
  int i = blockIdx.x * 256 + threadIdx.x;   // 12288 total
  float d = 0.f;
  if (i < NBAT * NKC * NC) d = ca[(size_t)NBAT * NKC * NC + i] - ca[i];
  float ss = blockReduceSum(d * d);
  if (threadIdx.x == 0) atomicAdd(out, ss * (0.0005f / 8.0f));
}

// ---------- 3b. pre-convert W (v|q|k) to bf16 Wb[320][256] ----------
__global__ __launch_bounds__(256)
void k_wconv(const float* __restrict__ wv, const float* __restrict__ wq,
             const float* __restrict__ wk, unsigned short* __restrict__ Wb){
  int n = blockIdx.x;         // 320
  const float* src = (n < 256) ? (wv + (size_t)n * NC)
                   : (n < 288) ? (wq + (size_t)(n - 256) * NC)
                               : (wk + (size_t)(n - 288) * NC);
  Wb[(size_t)n * NC + threadIdx.x] = f2bf(src[threadIdx.x]);
}

// ---------- 4. MFMA GEMM -> V1b[h][c][96w] (c-blocked-contiguous) + q,k [p][cq] ----------
__global__ __launch_bounds__(256)
void k_v(const unsigned short* __restrict__ XNT, const unsigned short* __restrict__ XNS,
         const unsigned short* __restrict__ Wb,
         const float* __restrict__ bv, const float* __restrict__ bq,
         const float* __restrict__ bk,
         unsigned short* __restrict__ V1T, unsigned short* __restrict__ V1S,
         unsigned short* __restrict__ qT, unsigned short* __restrict__ kT,
         unsigned short* __restrict__ qS, unsigned short* __restrict__ kS){
  int pt = blockIdx.x;                       // (144, 2*NB)
  int bb = blockIdx.y >> 1, ts = blockIdx.y & 1;
  const unsigned short* XN = (ts ? XNS : XNT) + (size_t)bb * NP * NC;
  unsigned short* V1 = (ts ? V1S : V1T) + (size_t)bb * NP * NC;
  unsigned short* qb  = (ts ? qS : qT) + (size_t)bb * NP * NCQ;
  unsigned short* kb  = (ts ? kS : kT) + (size_t)bb * NP * NCQ;
  int p0 = pt * 64;
  __shared__ unsigned short Wl[NV * 40];
  int lane = threadIdx.x & 63;
  int wid = threadIdx.x >> 6;
  int col = lane & 15, quad = lane >> 4;
  const unsigned short* xnb = XN + (size_t)(p0 + wid * 16 + col) * NC;
  floatx4 acc[20];
  #pragma unroll
  for (int nt = 0; nt < 20; nt++) acc[nt] = (floatx4){0.f, 0.f, 0.f, 0.f};

  int ci_n[5], ci_k8[5];
  #pragma unroll
  for (int i = 0; i < 5; i++){ int ci = i * 256 + threadIdx.x; ci_n[i] = ci >> 2; ci_k8[i] = (ci & 3) * 8; }

  short8 w[5];
  #pragma unroll
  for (int i = 0; i < 5; i++)
    w[i] = *(const short8*)(Wb + (size_t)ci_n[i] * NC + ci_k8[i]);

  for (int ks = 0; ks < 8; ks++){
    if (ks) __syncthreads();
    #pragma unroll
    for (int i = 0; i < 5; i++)
      *(short8*)(Wl + ci_n[i] * 40 + ci_k8[i]) = w[i];
    __syncthreads();
    if (ks < 7){
      int k0n = (ks + 1) * 32;
      #pragma unroll
      for (int i = 0; i < 5; i++)
        w[i] = *(const short8*)(Wb + (size_t)ci_n[i] * NC + k0n + ci_k8[i]);
    }
    short8 a = *(const short8*)(xnb + ks * 32 + quad * 8);
    #pragma unroll
    for (int nt = 0; nt < 20; nt++){
      short8 b = *(const short8*)(Wl + (nt * 16 + col) * 40 + quad * 8);
      acc[nt] = __builtin_amdgcn_mfma_f32_16x16x32_bf16(a, b, acc[nt], 0, 0, 0);
    }
  }

  int prow0 = p0 + wid * 16 + quad * 4;
  int hh = prow0 / 96, ww = prow0 % 96;     // 4-row group never crosses h (4 | 96)
  #pragma unroll
  for (int nt = 0; nt < 16; nt++){
    int c = nt * 16 + col;
    float bias = bv[c];
    uint2 u;
    u.x = (unsigned)f2bf(acc[nt][0] + bias) | ((unsigned)f2bf(acc[nt][1] + bias) << 16);
    u.y = (unsigned)f2bf(acc[nt][2] + bias) | ((unsigned)f2bf(acc[nt][3] + bias) << 16);
    *(uint2*)(V1 + ((size_t)(hh * 256 + c)) * 96 + ww) = u;
  }
  #pragma unroll
  for (int nt = 16; nt < 18; nt++){
    int c = (nt - 16) * 16 + col;
    float bias = bq[c];
    #pragma unroll
    for (int i = 0; i < 4; i++)
      qb[((size_t)(prow0 + i)) * NCQ + c] = f2bf(acc[nt][i] + bias);
  }
  #pragma unroll
  for (int nt = 18; nt < 20; nt++){
    int c = (nt - 18) * 16 + col;
    float bias = bk[c];
    #pragma unroll
    for (int i = 0; i < 4; i++)
      kb[((size_t)(prow0 + i)) * NCQ + c] = f2bf(acc[nt][i] + bias);
  }
}

// ---------- 4b. transpose V1b[h][c][w] -> V2b[w][c][h], 2 channels per block ----------
__global__ __launch_bounds__(256)
void k_vt(const unsigned short* __restrict__ V1T, const unsigned short* __restrict__ V1S,
          unsigned short* __restrict__ V2T, unsigned short* __restrict__ V2S){
  int cp = blockIdx.x;                       // (128, 2*NB)
  int bb = blockIdx.y >> 1, ts = blockIdx.y & 1;
  const unsigned short* V1 = (ts ? V1S : V1T) + (size_t)bb * NP * NC;
  unsigned short* V2 = (ts ? V2S : V2T) + (size_t)bb * NP * NC;
  int c0 = cp * 2;
  __shared__ unsigned short tile[2 * 96 * 104];   // [cl][w][h], 39.9 KB
  #pragma unroll
  for (int k = 0; k < 9; k++){
    int idx = threadIdx.x + k * 256;              // 2304 short8 chunks
    int cl = idx / 1152, rem = idx % 1152;
    int h = rem / 12, g = rem % 12;
    short8 v = *(const short8*)(V1 + ((size_t)(h * 256 + c0 + cl)) * 96 + g * 8);
    #pragma unroll
    for (int jj = 0; jj < 8; jj++)
      tile[cl * 9984 + (g * 8 + jj) * 104 + h] = ((unsigned short*)&v)[jj];
  }
  __syncthreads();
  #pragma unroll
  for (int k = 0; k < 9; k++){
    int idx = threadIdx.x + k * 256;
    int cl = idx / 1152, rem = idx % 1152;
    int w = rem / 12, g = rem % 12;
    short8 v = *(const short8*)(tile + cl * 9984 + w * 104 + g * 8);
    *(short8*)(V2 + ((size_t)(w * 256 + c0 + cl)) * 96 + g * 8) = v;
  }
}

// ---------- 5+6. scores -> attHt[w*96+i][96] (which=0, diag mask) / attW[p][96] (which=1)
__global__ __launch_bounds__(256)
void k_e(const unsigned short* __restrict__ qT, const unsigned short* __restrict__ kT,
         const unsigned short* __restrict__ qS, const unsigned short* __restrict__ kS,
         unsigned short* __restrict__ attHtT, unsigned short* __restrict__ attWT,
         unsigned short* __restrict__ attHtS, unsigned short* __restrict__ attWS){
  int x = blockIdx.x, which = blockIdx.z;    // (96, 2*NB, 2)
  int bb = blockIdx.y >> 1, ts = blockIdx.y & 1;
  const unsigned short* qb = (ts ? qS : qT) + (size_t)bb * NP * NCQ;
  const unsigned short* kb = (ts ? kS : kT) + (size_t)bb * NP * NCQ;
  unsigned short* att = (which ? (ts ? attWS : attWT) : (ts ? attHtS : attHtT))
                        + (size_t)bb * NP * 96;
  int lane = threadIdx.x & 63, wid = threadIdx.x >> 6;
  int col = lane & 15, quad = lane >> 4;
  int mi0 = (wid & 1) * 3, ni0 = (wid >> 1) * 3;
  short8 a[3], b[3];
  if (which == 0){            // eH: fixed w=x, queries (i,x)
    #pragma unroll
    for (int m = 0; m < 3; m++)
      a[m] = *(const short8*)(qb + ((size_t)(((mi0 + m) * 16 + col) * 96 + x)) * NCQ + quad * 8);
    #pragma unroll
    for (int n = 0; n < 3; n++)
      b[n] = *(const short8*)(kb + ((size_t)(((ni0 + n) * 16 + col) * 96 + x)) * NCQ + quad * 8);
  } else {                    // eW: fixed h=x, queries (x,i)
    #pragma unroll
    for (int m = 0; m < 3; m++)
      a[m] = *(const short8*)(qb + ((size_t)(x * 96 + (mi0 + m) * 16 + col)) * NCQ + quad * 8);
    #pragma unroll
    for (int n = 0; n < 3; n++)
      b[n] = *(const short8*)(kb + ((size_t)(x * 96 + (ni0 + n) * 16 + col)) * NCQ + quad * 8);
  }
  floatx4 acc[3][3];
  #pragma unroll
  for (int m = 0; m < 3; m++)
    #pragma unroll
    for (int n = 0; n < 3; n++){
      acc[m][n] = (floatx4){0.f, 0.f, 0.f, 0.f};
      acc[m][n] = __builtin_amdgcn_mfma_f32_16x16x32_bf16(a[m], b[n], acc[m][n], 0, 0, 0);
    }
  #pragma unroll
  for (int m = 0; m < 3; m++)
    #pragma unroll
    for (int n = 0; n < 3; n++){
      int j = (ni0 + n) * 16 + col;
      #pragma unroll
      for (int r = 0; r < 4; r++){
        int i = (mi0 + m) * 16 + quad * 4 + r;
        float v = (!which && j == i) ? -INFINITY : acc[m][n][r];
        att[((size_t)(x * 96 + i)) * 96 + j] = f2bf(v);   // contiguous slab per block
      }
    }
}

// ---------- 7. softmax over 192 per query (across attHt + attW planes) ----------
__global__ __launch_bounds__(256)
void k_attSoftmax(unsigned short* __restrict__ attHtT, unsigned short* __restrict__ attWT,
                  unsigned short* __restrict__ attHtS, unsigned short* __restrict__ attWS,
                  int nbp){                   // nbp = NB*NP
  int q = blockIdx.x * 4 + (threadIdx.x >> 6);
  int lane = threadIdx.x & 63;
  int sS = (q >= nbp);
  int ql = sS ? q - nbp : q;
  unsigned short* aHt = sS ? attHtS : attHtT;
  unsigned short* aW  = sS ? attWS  : attWT;
  int bb = ql / NP, p = ql % NP;
  unsigned short* rowW = aW  + ((size_t)(bb * NP + p)) * 96;
  unsigned short* rowH = aHt + ((size_t)(bb * NP + (p % 96) * 96 + p / 96)) * 96;
  float h0 = bf2f(rowH[lane]);
  float w0 = bf2f(rowW[lane]);
  float h1 = (lane < 32) ? bf2f(rowH[64 + lane]) : -INFINITY;
  float w1 = (lane < 32) ? bf2f(rowW[64 + lane]) : -INFINITY;
  float m = fmaxf(fmaxf(h0, h1), fmaxf(w0, w1));
  m = warpReduceMax(m);
  float xh0 = expf(h0 - m), xw0 = expf(w0 - m);
  float xh1 = (lane < 32) ? expf(h1 - m) : 0.f;
  float xw1 = (lane < 32) ? expf(w1 - m) : 0.f;
  float s = warpReduceSum(xh0 + xw0 + xh1 + xw1);
  float rs = 1.f / s;
  rowH[lane] = f2bf(xh0 * rs);
  rowW[lane] = f2bf(xw0 * rs);
  if (lane < 32){
    rowH[64 + lane] = f2bf(xh1 * rs);
    rowW[64 + lane] = f2bf(xw1 * rs);
  }
}

// ---------- 8. outH: OHb[cs][i*96+w][64c] = attHt[w-slab] x V2b[w][c][h] ----------
__global__ __launch_bounds__(256)
void k_outH(const unsigned short* __restrict__ V2T, const unsigned short* __restrict__ V2S,
            const unsigned short* __restrict__ attHtT, const unsigned short* __restrict__ attHtS,
            unsigned short* __restrict__ OHT, unsigned short* __restrict__ OHS){
  int w = blockIdx.x, cs = blockIdx.z;       // (96, 2*NB, 4)
  int bb = blockIdx.y >> 1, ts = blockIdx.y & 1;
  const unsigned short* V2 = (ts ? V2S : V2T) + (size_t)bb * NP * NC;
  const unsigned short* att = (ts ? attHtS : attHtT) + (size_t)bb * NP * 96;
  unsigned short* OH = (ts ? OHS : OHT) + (size_t)bb * NP * NC + (size_t)cs * NP * 64;
  int lane = threadIdx.x & 63, wid = threadIdx.x >> 6;
  int col = lane & 15, quad = lane >> 4;
  int cl = wid * 16 + col;
  int c = cs * 64 + cl;
  floatx4 acc[6];
  #pragma unroll
  for (int m = 0; m < 6; m++) acc[m] = (floatx4){0.f, 0.f, 0.f, 0.f};
  #pragma unroll
  for (int ks = 0; ks < 3; ks++){
    int k0 = ks * 32 + quad * 8;
    short8 a[6], b;
    #pragma unroll
    for (int m = 0; m < 6; m++)
      a[m] = *(const short8*)(att + ((size_t)(w * 96 + m * 16 + col)) * 96 + k0);
    b = *(const short8*)(V2 + ((size_t)(w * 256 + c)) * 96 + k0);
    #pragma unroll
    for (int m = 0; m < 6; m++)
      acc[m] = __builtin_amdgcn_mfma_f32_16x16x32_bf16(a[m], b, acc[m], 0, 0, 0);
  }
  #pragma unroll
  for (int m = 0; m < 6; m++){
    #pragma unroll
    for (int r = 0; r < 4; r++){
      int i = m * 16 + quad * 4 + r;
      OH[((size_t)(i * 96 + w)) * 64 + cl] = f2bf(acc[m][r]);
    }
  }
}

// ---------- 9. combined outW(T,S) + fused loss; dn read from DN plane ----------
__global__ __launch_bounds__(256)
void k_outWL(const unsigned short* __restrict__ V1T, const unsigned short* __restrict__ attWT,
             const unsigned short* __restrict__ OHT,
             const unsigned short* __restrict__ V1S, const unsigned short* __restrict__ attWS,
             const unsigned short* __restrict__ OHS,
             const unsigned short* __restrict__ DN,
             const float* __restrict__ gamma,
             float* __restrict__ out){
  int h = blockIdx.x, bb = blockIdx.y, cs = blockIdx.z;    // (96, NB, 4)
  size_t pb = (size_t)bb * NP * NC;
  int lane = threadIdx.x & 63, wid = threadIdx.x >> 6;
  int col = lane & 15, quad = lane >> 4;
  int cl = wid * 16 + col;
  int c  = cs * 64 + cl;

  __shared__ unsigned short ohTl[96 * 72];   // [i][cl], stride 72
  __shared__ unsigned short ohSl[96 * 72];
  __shared__ unsigned short dnl [96 * 72];

  const unsigned short* OHTb = OHT + pb + (size_t)cs * NP * 64 + (size_t)(h * 96) * 64;
  const unsigned short* OHSb = OHS + pb + (size_t)cs * NP * 64 + (size_t)(h * 96) * 64;
  const unsigned short* DNb  = DN + pb;
  #pragma unroll
  for (int k = 0; k < 3; k++){
    int g = threadIdx.x + k * 256;           // 768 x 16B, OH slabs fully linear
    int i = g >> 3, cc = (g & 7) * 8;
    short8 ot = *(const short8*)(OHTb + g * 8);
    short8 os = *(const short8*)(OHSb + g * 8);
    short8 dn = *(const short8*)(DNb + ((size_t)(h * 96 + i)) * NC + cs * 64 + cc);
    *(short8*)(ohTl + i * 72 + cc) = ot;
    *(short8*)(ohSl + i * 72 + cc) = os;
    *(short8*)(dnl  + i * 72 + cc) = dn;
  }
  __syncthreads();

  floatx4 accT[6], accS[6];
  #pragma unroll
  for (int m = 0; m < 6; m++){
    accT[m] = (floatx4){0.f, 0.f, 0.f, 0.f};
    accS[m] = (floatx4){0.f, 0.f, 0.f, 0.f};
  }
  #pragma unroll
  for (int ks = 0; ks < 3; ks++){
    int k0 = ks * 32 + quad * 8;
    short8 a[6], b;
    #pragma unroll
    for (int m = 0; m < 6; m++)
      a[m] = *(const short8*)(attWT + (size_t)bb * NP * 96 + ((size_t)(h * 96 + m * 16 + col)) * 96 + k0);
    b = *(const short8*)(V1T + pb + ((size_t)(h * 256 + c)) * 96 + k0);
    #pragma unroll
    for (int m = 0; m < 6; m++)
      accT[m] = __builtin_amdgcn_mfma_f32_16x16x32_bf16(a[m], b, accT[m], 0, 0, 0);
  }
  #pragma unroll
  for (int ks = 0; ks < 3; ks++){
    int k0 = ks * 32 + quad * 8;
    short8 a[6], b;
    #pragma unroll
    for (int m = 0; m < 6; m++)
      a[m] = *(const short8*)(attWS + (size_t)bb * NP * 96 + ((size_t)(h * 96 + m * 16 + col)) * 96 + k0);
    b = *(const short8*)(V1S + pb + ((size_t)(h * 256 + c)) * 96 + k0);
    #pragma unroll
    for (int m = 0; m < 6; m++)
      accS[m] = __builtin_amdgcn_mfma_f32_16x16x32_bf16(a[m], b, accS[m], 0, 0, 0);
  }

  float g = gamma[0];
  float ss = 0.f;
  #pragma unroll
  for (int m = 0; m < 6; m++){
    int i0 = m * 16 + quad * 4;
    #pragma unroll
    for (int r = 0; r < 4; r++){
      int i = i0 + r;
      float oT = accT[m][r] + bf2f(ohTl[i * 72 + cl]);
      float oS = accS[m][r] + bf2f(ohSl[i * 72 + cl]);
      float d = g * (oT - oS) + bf2f(dnl[i * 72 + cl]);
      ss += d * d;
    }
  }
  ss = blockReduceSum(ss);
  if (threadIdx.x == 0) atomicAdd(out, ss * (1e-5f / 8.0f));
}

// ---------- host ----------
extern "C" void kernel_launch(void* const* d_in, const int* in_sizes, int n_in,
                              void* d_out, int out_size, void* d_ws, size_t ws_size,
                              hipStream_t stream){
  (void)in_sizes; (void)n_in; (void)out_size;
  const float* S    = (const float*)d_in[0];
  const float* T    = (const float*)d_in[1];
  const float* wcls = (const float*)d_in[2];
  const float* wq   = (const float*)d_in[3];
  const float* bq   = (const float*)d_in[4];
  const float* wk   = (const float*)d_in[5];
  const float* bk   = (const float*)d_in[6];
  const float* wv   = (const float*)d_in[7];
  const float* bv   = (const float*)d_in[8];
  const float* gamma= (const float*)d_in[9];
  float* out = (float*)d_out;

  char* base = (char*)d_ws;
  size_t off = 0;
  auto alloc = [&](size_t b){ size_t o = off; off += (b + 255) & ~(size_t)255; return o; };
  size_t o_ssum = alloc(2 * NC * 4);
  size_t o_ssq  = alloc(2 * NC * 4);
  size_t o_mean = alloc(2 * NC * 4);
  size_t o_inv  = alloc(2 * NC * 4);
  size_t o_wb   = alloc((size_t)NV * NC * 2);
  size_t o_ca   = alloc((size_t)2 * NBAT * NKC * NC * 4);
  size_t o_smca = alloc((size_t)2 * NBAT * NKC * NP * 4);
  size_t fixed = off;

  const size_t PB  = (size_t)NP * NC * 2;     // 4.72 MB bf16 plane
  const size_t AT1 = (size_t)NP * 96 * 2;     // 1.77 MB att half-plane
  const size_t QB  = (size_t)NP * NCQ * 2;    // 0.59 MB
  // planes: XNT, XNS, DN, V1T, V1S, OHT, OHS (V2 aliases XN after k_v)
  size_t per_b = 7 * PB + 4 * AT1 + 4 * QB;   // 42.5 MB per batch
  int NB = 8;
  while (NB > 1 && fixed + (size_t)NB * per_b + 8192 > ws_size) NB >>= 1;

  size_t o_xnT = alloc((size_t)NB * PB);
  size_t o_xnS = alloc((size_t)NB * PB);
  size_t o_dn  = alloc((size_t)NB * PB);
  size_t o_v1T = alloc((size_t)NB * PB);
  size_t o_v1S = alloc((size_t)NB * PB);
  size_t o_ohT = alloc((size_t)NB * PB);
  size_t o_ohS = alloc((size_t)NB * PB);
  size_t o_hT  = alloc((size_t)NB * AT1);
  size_t o_wT  = alloc((size_t)NB * AT1);
  size_t o_hS  = alloc((size_t)NB * AT1);
  size_t o_wS  = alloc((size_t)NB * AT1);
  size_t o_qT  = alloc((size_t)NB * QB);
  size_t o_kT  = alloc((size_t)NB * QB);
  size_t o_qS  = alloc((size_t)NB * QB);
  size_t o_kS  = alloc((size_t)NB * QB);

  float* ssum = (float*)(base + o_ssum);
  float* ssq  = (float*)(base + o_ssq);
  float* mean = (float*)(base + o_mean);
  float* inv  = (float*)(base + o_inv);
  float* ca   = (float*)(base + o_ca);
  float* smca = (float*)(base + o_smca);
  unsigned short* Wb   = (unsigned short*)(base + o_wb);
  unsigned short* XNT  = (unsigned short*)(base + o_xnT);
  unsigned short* XNS  = (unsigned short*)(base + o_xnS);
  unsigned short* DN   = (unsigned short*)(base + o_dn);
  unsigned short* V1T  = (unsigned short*)(base + o_v1T);
  unsigned short* V1S  = (unsigned short*)(base + o_v1S);
  unsigned short* V2T  = XNT;                 // alias: XN dead after k_v
  unsigned short* V2S  = XNS;
  unsigned short* OHT  = (unsigned short*)(base + o_ohT);
  unsigned short* OHS  = (unsigned short*)(base + o_ohS);
  unsigned short* aHtT = (unsigned short*)(base + o_hT);
  unsigned short* aWT  = (unsigned short*)(base + o_wT);
  unsigned short* aHtS = (unsigned short*)(base + o_hS);
  unsigned short* aWS  = (unsigned short*)(base + o_wS);
  unsigned short* qT   = (unsigned short*)(base + o_qT);
  unsigned short* kT   = (unsigned short*)(base + o_kT);
  unsigned short* qS   = (unsigned short*)(base + o_qS);
  unsigned short* kS   = (unsigned short*)(base + o_kS);

  hipMemsetAsync(d_out, 0, 4, stream);
  hipMemsetAsync(base + o_ssum, 0, 4096, stream);
  hipMemsetAsync(base + o_ca, 0, (size_t)2 * NBAT * NKC * NC * 4, stream);
  hipMemsetAsync(base + o_smca, 0, (size_t)2 * NBAT * NKC * NP * 4, stream);

  k_stats<<<dim3(2 * NC * NBAT), 256, 0, stream>>>(S, T, ssum, ssq);
  k_finalize<<<1, 512, 0, stream>>>(ssum, ssq, mean, inv);
  k_wconv<<<dim3(NV), 256, 0, stream>>>(wv, wq, wk, Wb);

  for (int b0 = 0; b0 < NBAT; b0 += NB){
    k_xn<<<dim3(144, 4, NB), 256, 0, stream>>>(S, T, b0, mean, inv, wcls,
                                               XNT, XNS, DN, smca);
    k_caSoftmax<<<dim3(2 * NB * NKC), 256, 0, stream>>>(smca, b0);
    k_caOut<<<dim3(36, NB, 2), 256, 0, stream>>>(XNT, XNS, smca, b0, ca);
    k_v<<<dim3(144, 2 * NB), 256, 0, stream>>>(XNT, XNS, Wb, bv, bq, bk,
                                               V1T, V1S, qT, kT, qS, kS);
    k_vt<<<dim3(128, 2 * NB), 256, 0, stream>>>(V1T, V1S, V2T, V2S);
    k_e<<<dim3(96, 2 * NB, 2), 256, 0, stream>>>(qT, kT, qS, kS, aHtT, aWT, aHtS, aWS);
    k_attSoftmax<<<dim3(2 * NB * NP / 4), 256, 0, stream>>>(aHtT, aWT, aHtS, aWS, NB * NP);
    k_outH<<<dim3(96, 2 * NB, 4), 256, 0, stream>>>(V2T, V2S, aHtT, aHtS, OHT, OHS);
    k_outWL<<<dim3(96, NB, 4), 256, 0, stream>>>(V1T, aWT, OHT, V1S, aWS, OHS,
                                                 DN, gamma, out);
  }
  k_caLoss<<<dim3(48), 256, 0, stream>>>(ca, out);
}